// Round 14
// baseline (518.117 us; speedup 1.0000x reference)
//
#include <hip/hip_runtime.h>
#include <hip/hip_fp16.h>

#define HH 4096
#define WW 4096

constexpr float C_LAM = 0.1f;   // ALPHA * LAMDA
constexpr float TAU_F = 0.25f;

// ---- first-iteration kernel geometry ----
#define BX 64
#define BY 8
#define VEC 4
#define TILE_W (BX * VEC)       // 256 cols per block

// ---- tv_last (2-ring) geometry ----
#define TW2 64
#define TH2 32
#define ERR 36
#define ECC 72
#define NCH (ECC / 4)
#define NSL (ERR * NCH)         // 648
#define LSZ (ERR * ECC)         // 2592

// ---- tv_iter8 (8-step, register-strip) geometry ----
// Each thread owns 4 rows x 8 px in REGISTERS. LDS holds only strip-boundary
// rows (px row3 / u row0) and packed chunk-edge columns (py7 / u0).
// R13 lesson: __launch_bounds__(128) alone capped VGPRs at 64 -> the 64-reg
// strip state went to AGPRs -> v_accvgpr_read/write on every access (~2x
// VALU). (128, 4) raises the cap to 128 VGPRs so state stays in real VGPRs.
#define TH8 32                  // interior rows
#define TW8 64                  // interior cols
#define XC8 80                  // extended cols [c0-8, c0+71]
#define NS8 12                  // 4-row strips over 48 extended rows
#define NQ8 10                  // 8-px chunks per row
#define NT8 120                 // active threads = NS8*NQ8

typedef float    __attribute__((ext_vector_type(4))) f32x4_t;
typedef float    __attribute__((ext_vector_type(2))) f32x2_t;
typedef unsigned __attribute__((ext_vector_type(2))) u32x2_t;

union H2x4 { float4 f4; f32x4_t v4; __half2 h2[4]; unsigned u32[4]; };
union H2x2 { float2 f2; f32x2_t v2; __half2 h2[2]; unsigned u32[2]; };
union H2U  { __half2 h; unsigned int u; };

__device__ __forceinline__ float clip1(float v) {
    return fminf(1.0f, fmaxf(-1.0f, v));
}

__device__ __forceinline__ unsigned h2u(__half2 h) { H2U a; a.h = h; return a.u; }
__device__ __forceinline__ __half2  u2h(unsigned u){ H2U a; a.u = u; return a.h; }

// v_perm_b32: result bytes select from {a(hi):b(lo)}; sel byte i in 0-3 -> b, 4-7 -> a
__device__ __forceinline__ __half2 permh(__half2 a, __half2 b, unsigned sel) {
    unsigned d;
    asm("v_perm_b32 %0, %1, %2, %3" : "=v"(d) : "v"(h2u(a)), "v"(h2u(b)), "v"(sel));
    return u2h(d);
}
__device__ __forceinline__ __half2 andh(__half2 v, unsigned m) { return u2h(h2u(v) & m); }

// packed clamp to [-1,1] (no __hmax2/__hmin2 in ROCm 7.2 headers)
__device__ __forceinline__ __half2 clamp1h2(__half2 v) {
    H2U a; a.h = v;
    unsigned int lo = 0xBC00BC00u;   // (-1, -1) fp16
    unsigned int hi = 0x3C003C00u;   // (+1, +1) fp16
    unsigned int t, r;
    asm("v_pk_max_f16 %0, %1, %2" : "=v"(t) : "v"(a.u), "v"(lo));
    asm("v_pk_min_f16 %0, %1, %2" : "=v"(r) : "v"(t),   "v"(hi));
    H2U b; b.u = r;
    return b.h;
}

__device__ __forceinline__ __half2 shfl_up_h2(__half2 v) {
    H2U a; a.h = v;
    int s = __shfl_up((int)a.u, 1, 64);
    H2U b; b.u = (unsigned)s;
    return b.h;
}

// (hi:lo) >> 16, as __half2: result = (lo.hi, hi.lo)
__device__ __forceinline__ __half2 align16(__half2 hi, __half2 lo) {
    H2U a, b, d;
    a.h = hi; b.h = lo;
    asm("v_alignbit_b32 %0, %1, %2, 16" : "=v"(d.u) : "v"(a.u), "v"(b.u));
    return d.h;
}

// iteration 0 (p=0 -> u=x):  p = clip(tau * grad(x)); also emits x_h = fp16(x)
__global__ __launch_bounds__(512) void tv_first(const float* __restrict__ x,
                                                __half2* __restrict__ po,
                                                __half* __restrict__ xh)
{
    const int tx = threadIdx.x, ty = threadIdx.y;
    const int i = blockIdx.y * BY + ty;
    const int j = blockIdx.x * TILE_W + tx * VEC;
    const size_t idx = (size_t)i * WW + j;

    float4 xc4 = *(const float4*)(x + idx);
    float4 xd4 = make_float4(0.f, 0.f, 0.f, 0.f);
    if (i < HH - 1) xd4 = *(const float4*)(x + idx + WW);

    float c[4] = {xc4.x, xc4.y, xc4.z, xc4.w};
    float d[4] = {xd4.x, xd4.y, xd4.z, xd4.w};

    float xr = __shfl_down(c[0], 1, 64);
    if (tx == BX - 1 && j + VEC < WW) xr = x[idx + VEC];

    H2x4 o;
#pragma unroll
    for (int e = 0; e < 4; ++e) {
        float gx = (i < HH - 1) ? (d[e] - c[e]) : 0.f;
        float rn = (e < 3) ? c[e + 1] : xr;
        float gy = (j + e < WW - 1) ? (rn - c[e]) : 0.f;
        o.h2[e] = __floats2half2_rn(clip1(TAU_F * gx), clip1(TAU_F * gy));
    }
    *(float4*)(po + idx) = o.f4;

    H2x2 xs;
    xs.h2[0] = __floats2half2_rn(c[0], c[1]);
    xs.h2[1] = __floats2half2_rn(c[2], c[3]);
    *(float2*)(xh + idx) = xs.f2;
}

// -------- eight fused Chambolle steps, register-strip decomposition --------
template<bool EDGE>
__device__ __forceinline__ void iter8_body(const __half* __restrict__ xh,
                                           const __half2* __restrict__ pi,
                                           __half2* __restrict__ po,
                                           __half* pxB, __half* uT,
                                           unsigned* pyE, unsigned* uE)
{
    const int tid = threadIdx.x;
    const bool act = (tid < NT8);
    const int t = act ? tid : (NT8 - 1);
    const int s = t / NQ8;
    const int q = t - s * NQ8;
    const int r0 = blockIdx.y * TH8, c0 = blockIdx.x * TW8;
    const int gi0 = r0 - 8 + 4 * s;              // global row of strip row 0
    const int gj0 = c0 - 8 + 8 * q;              // global col of chunk elem 0
    const int gjc = EDGE ? min(max(gj0, 0), WW - 8) : gj0;

    const int lB  = s * XC8 + 8 * q;             // own boundary-row slot
    const int lBu = ((s > 0) ? (s - 1) : 0) * XC8 + 8 * q;
    const int lBd = ((s < NS8 - 1) ? (s + 1) : s) * XC8 + 8 * q;
    const int eO = t * 2;                        // packed edge (u32 index)
    const int eL = ((q > 0) ? (t - 1) : t) * 2;
    const int eR = ((q < NQ8 - 1) ? (t + 1) : t) * 2;
    const bool wout = act && (s >= 2) && (s <= 9) && (q >= 1) && (q <= 8);

    unsigned mdy = 0xFFFFFFFFu, mgy = 0xFFFFFFFFu;
    if (EDGE) {
        if (gj0 == 0)      mdy = 0xFFFF0000u;    // zero dy at global col 0
        if (gj0 + 8 == WW) mgy = 0x0000FFFFu;    // zero gy at global col WW-1
    }

    const __half2 tau2 = __float2half2_rn(TAU_F);
    const __half2 nC2  = __float2half2_rn(-C_LAM);
    const unsigned SEL0 = 0x05040100u;   // (b.lo16, a.lo16)
    const unsigned SELH = 0x07060302u;   // (b.hi16, a.hi16)
    const unsigned SELM = 0x05040302u;   // (b.hi16, a.lo16)

    __half2 X[4][4], Y[4][4], XHr[4][4], U[4][4];

    // ---- stage A: load interleaved p + xh; deinterleave into registers ----
#pragma unroll
    for (int k = 0; k < 4; ++k) {
        int gik = gi0 + k;
        if (EDGE) gik = min(max(gik, 0), HH - 1);
        const size_t go = (size_t)gik * WW + gjc;
        H2x4 v0; v0.v4 = *(const f32x4_t*)(pi + go);
        H2x4 v1; v1.v4 = *(const f32x4_t*)(pi + go + 4);
        H2x4 xv; xv.v4 = *(const f32x4_t*)(xh + go);
        X[k][0] = permh(v0.h2[1], v0.h2[0], SEL0);
        Y[k][0] = permh(v0.h2[1], v0.h2[0], SELH);
        X[k][1] = permh(v0.h2[3], v0.h2[2], SEL0);
        Y[k][1] = permh(v0.h2[3], v0.h2[2], SELH);
        X[k][2] = permh(v1.h2[1], v1.h2[0], SEL0);
        Y[k][2] = permh(v1.h2[1], v1.h2[0], SELH);
        X[k][3] = permh(v1.h2[3], v1.h2[2], SEL0);
        Y[k][3] = permh(v1.h2[3], v1.h2[2], SELH);
#pragma unroll
        for (int m = 0; m < 4; ++m) XHr[k][m] = xv.h2[m];
    }

#pragma unroll
    for (int it = 0; it < 8; ++it) {
        const bool last = (it == 7);

        // ---- publish p boundaries (px row3 full; py7 edges packed) ----
        if (act) {
            H2x4 w;
#pragma unroll
            for (int m = 0; m < 4; ++m) w.h2[m] = X[3][m];
            *(f32x4_t*)(pxB + lB) = w.v4;
            u32x2_t e;
            e.x = h2u(permh(Y[1][3], Y[0][3], SELH));   // (py7 r0, py7 r1)
            e.y = h2u(permh(Y[3][3], Y[2][3], SELH));   // (py7 r2, py7 r3)
            *(u32x2_t*)(pyE + eO) = e;
        }
        __syncthreads();

        // ---- u-stage: u = xh - C*div(p) ----
        {
            H2x4 pu; pu.v4 = *(const f32x4_t*)(pxB + lBu);
            u32x2_t Lp = *(const u32x2_t*)(pyE + eL);
            const __half2 L0 = u2h(Lp.x), L1 = u2h(Lp.y);
#pragma unroll
            for (int k = 0; k < 4; ++k) {
                __half2 dx[4], zm[4], dy[4];
#pragma unroll
                for (int m = 0; m < 4; ++m)
                    dx[m] = __hsub2((k == 0) ? pu.h2[m] : X[k - 1][m], X[k][m]);
                if (EDGE && !(gi0 + k > 0)) {
#pragma unroll
                    for (int m = 0; m < 4; ++m) dx[m] = u2h(0u);
                }
                zm[0] = (k == 0) ? permh(Y[k][0], L0, SEL0)
                      : (k == 1) ? permh(Y[k][0], L0, SELM)
                      : (k == 2) ? permh(Y[k][0], L1, SEL0)
                                 : permh(Y[k][0], L1, SELM);
                zm[1] = align16(Y[k][1], Y[k][0]);
                zm[2] = align16(Y[k][2], Y[k][1]);
                zm[3] = align16(Y[k][3], Y[k][2]);
#pragma unroll
                for (int m = 0; m < 4; ++m) dy[m] = __hsub2(zm[m], Y[k][m]);
                if (EDGE) dy[0] = andh(dy[0], mdy);
#pragma unroll
                for (int m = 0; m < 4; ++m)
                    U[k][m] = __hfma2(__hadd2(dx[m], dy[m]), nC2, XHr[k][m]);
            }
            if (act) {
                H2x4 w;
#pragma unroll
                for (int m = 0; m < 4; ++m) w.h2[m] = U[0][m];
                *(f32x4_t*)(uT + lB) = w.v4;
                u32x2_t e;
                e.x = h2u(permh(U[1][0], U[0][0], SEL0));   // (u0 r0, u0 r1)
                e.y = h2u(permh(U[3][0], U[2][0], SEL0));   // (u0 r2, u0 r3)
                *(u32x2_t*)(uE + eO) = e;
            }
        }
        __syncthreads();

        // ---- p-stage: p = clip(p + tau*grad(u)) ----
        {
            H2x4 ud; ud.v4 = *(const f32x4_t*)(uT + lBd);
            u32x2_t Rp = *(const u32x2_t*)(uE + eR);
            const __half2 R0 = u2h(Rp.x), R1 = u2h(Rp.y);
#pragma unroll
            for (int k = 0; k < 4; ++k) {
                __half2 gx[4], zp[4], gy[4];
#pragma unroll
                for (int m = 0; m < 4; ++m)
                    gx[m] = __hsub2((k == 3) ? ud.h2[m] : U[k + 1][m], U[k][m]);
                if (EDGE && !(gi0 + k < HH - 1)) {
#pragma unroll
                    for (int m = 0; m < 4; ++m) gx[m] = u2h(0u);
                }
                zp[0] = align16(U[k][1], U[k][0]);
                zp[1] = align16(U[k][2], U[k][1]);
                zp[2] = align16(U[k][3], U[k][2]);
                zp[3] = (k == 0) ? permh(R0, U[k][3], SELM)   // (u7, uR0 r0)
                      : (k == 1) ? permh(R0, U[k][3], SELH)
                      : (k == 2) ? permh(R1, U[k][3], SELM)
                                 : permh(R1, U[k][3], SELH);
#pragma unroll
                for (int m = 0; m < 4; ++m) gy[m] = __hsub2(zp[m], U[k][m]);
                if (EDGE) gy[3] = andh(gy[3], mgy);
#pragma unroll
                for (int m = 0; m < 4; ++m) {
                    X[k][m] = clamp1h2(__hfma2(gx[m], tau2, X[k][m]));
                    Y[k][m] = clamp1h2(__hfma2(gy[m], tau2, Y[k][m]));
                }
            }
        }

        if (last && wout) {
#pragma unroll
            for (int k = 0; k < 4; ++k) {
                const size_t go = (size_t)(gi0 + k) * WW + gj0;
                H2x4 w0, w1;
                w0.h2[0] = permh(Y[k][0], X[k][0], SEL0);   // (px0, py0)
                w0.h2[1] = permh(Y[k][0], X[k][0], SELH);   // (px1, py1)
                w0.h2[2] = permh(Y[k][1], X[k][1], SEL0);
                w0.h2[3] = permh(Y[k][1], X[k][1], SELH);
                w1.h2[0] = permh(Y[k][2], X[k][2], SEL0);
                w1.h2[1] = permh(Y[k][2], X[k][2], SELH);
                w1.h2[2] = permh(Y[k][3], X[k][3], SEL0);
                w1.h2[3] = permh(Y[k][3], X[k][3], SELH);
                *(f32x4_t*)(po + go)     = w0.v4;
                *(f32x4_t*)(po + go + 4) = w1.v4;
            }
        }
    }
}

// (128, 4): min 4 waves/EU -> VGPR cap 128 -> strip state stays in VGPRs
// (with plain (128) the compiler capped at 64 VGPR and bounced the state
// through AGPRs: v_accvgpr moves ~doubled VALU; R13 measured VGPR_Count=52).
__global__ __launch_bounds__(128, 4) void tv_iter8(const __half* __restrict__ xh,
                                                   const __half2* __restrict__ pi,
                                                   __half2* __restrict__ po)
{
    __shared__ __align__(16) __half   pxB[NS8 * XC8];
    __shared__ __align__(16) __half   uT [NS8 * XC8];
    __shared__ __align__(8)  unsigned pyE[NT8 * 2];
    __shared__ __align__(8)  unsigned uE [NT8 * 2];

    const bool edge = (blockIdx.x == 0) || (blockIdx.x == gridDim.x - 1) ||
                      (blockIdx.y == 0) || (blockIdx.y == gridDim.y - 1);
    if (!edge) iter8_body<false>(xh, pi, po, pxB, uT, pyE, uE);
    else       iter8_body<true >(xh, pi, po, pxB, uT, pyE, uE);
}

// -------- final: one more p-update (p49 -> p50) fused with the output --------
__global__ __launch_bounds__(256) void tv_last(const __half* __restrict__ xh,
                                               const float* __restrict__ x,
                                               const __half2* __restrict__ pi,
                                               float* __restrict__ out)
{
    __shared__ __half2 sp0[LSZ];
    __shared__ __half2 sp1[LSZ];
    __shared__ float   su [LSZ];

    const int tid  = threadIdx.x;
    const int lane = tid & 63;
    const int r0 = blockIdx.y * TH2;
    const int c0 = blockIdx.x * TW2;
    const __half2 tau2 = __float2half2_rn(TAU_F);

    int lb[3], lup[3], llf[3], ldn[3], lrt[3], gj0a[3], gofs[3];
    bool wr[3];
#pragma unroll
    for (int r = 0; r < 3; ++r) {
        int slot = tid + 256 * r;
        wr[r] = (slot < NSL);
        if (slot >= NSL) slot = NSL - 1;
        int cr = slot / NCH;
        int cc = slot - cr * NCH;
        int gi  = r0 - 2 + cr;
        int gj0 = c0 - 4 + cc * 4;
        int gic = min(max(gi, 0), HH - 1);
        int gjc = min(max(gj0, 0), WW - 4);
        gofs[r] = gic * WW + gjc;
        int l   = cr * ECC + cc * 4;
        lb[r]  = l;
        lup[r] = (cr > 0) ? l - ECC : l;
        llf[r] = (l > 0) ? l - 1 : 0;
        ldn[r] = (cr < ERR - 1) ? l + ECC : l;
        lrt[r] = min(l + 4, LSZ - 1);
        gj0a[r] = gj0;
    }

    __half2 c2[3][4];
    H2x2    xc[3];
#pragma unroll
    for (int r = 0; r < 3; ++r) {
        H2x4 v; v.f4 = *(const float4*)(pi + gofs[r]);
        xc[r].f2    = *(const float2*)(xh + gofs[r]);
        if (wr[r]) *(float4*)&sp0[lb[r]] = v.f4;
        c2[r][0] = v.h2[0]; c2[r][1] = v.h2[1];
        c2[r][2] = v.h2[2]; c2[r][3] = v.h2[3];
    }
    __syncthreads();

    float u1v[3][4];
#pragma unroll
    for (int r = 0; r < 3; ++r) {
        H2x4 up; up.f4 = *(float4*)&sp0[lup[r]];
        __half2 lf = shfl_up_h2(c2[r][3]);
        if (lane == 0) lf = sp0[llf[r]];
        float xs[4] = {__low2float(xc[r].h2[0]), __high2float(xc[r].h2[0]),
                       __low2float(xc[r].h2[1]), __high2float(xc[r].h2[1])};
        float4 w;
        float* wp = &w.x;
#pragma unroll
        for (int e = 0; e < 4; ++e) {
            __half2 cc = c2[r][e];
            __half2 le = (e == 0) ? lf : c2[r][e - 1];
            float dx = __low2float(up.h2[e]) - __low2float(cc);
            float dy = __high2float(le) - __high2float(cc);
            dy = (gj0a[r] + e > 0) ? dy : 0.f;
            float u = xs[e] - C_LAM * (dx + dy);
            u1v[r][e] = u;
            wp[e] = u;
        }
        if (wr[r]) *(float4*)&su[lb[r]] = w;
    }
    __syncthreads();

#pragma unroll
    for (int r = 0; r < 3; ++r) {
        float4 dn4 = *(float4*)&su[ldn[r]];
        float urr = __shfl_down(u1v[r][0], 1, 64);
        if (lane == 63) urr = su[lrt[r]];
        float dn[4] = {dn4.x, dn4.y, dn4.z, dn4.w};
        H2x4 w;
#pragma unroll
        for (int e = 0; e < 4; ++e) {
            float uc = u1v[r][e];
            float gx = dn[e] - uc;
            float rt = (e == 3) ? urr : u1v[r][e + 1];
            float gy = (gj0a[r] + e < WW - 1) ? (rt - uc) : 0.f;
            __half2 g = __float22half2_rn(make_float2(gx, gy));
            w.h2[e] = clamp1h2(__hfma2(g, tau2, c2[r][e]));
        }
        if (wr[r]) *(float4*)&sp1[lb[r]] = w.f4;
    }
    __syncthreads();

    // out = x - c*div(p50) on interior
#pragma unroll
    for (int r = 0; r < 2; ++r) {
        int slot = tid + 256 * r;
        int ir = slot >> 4, icc = slot & 15;
        int er = ir + 2, ec = icc * 4 + 4;
        int l  = er * ECC + ec;
        int gi = r0 + ir, gj = c0 + icc * 4;

        H2x4 pc_; pc_.f4 = *(float4*)&sp1[l];
        H2x4 pu_; pu_.f4 = *(float4*)&sp1[l - ECC];
        __half2 plf = shfl_up_h2(pc_.h2[3]);
        if ((tid & 15) == 0) plf = sp1[l - 1];

        float4 xr4 = *(const float4*)(x + (size_t)gi * WW + gj);
        float xv[4] = {xr4.x, xr4.y, xr4.z, xr4.w};
        float o[4];
#pragma unroll
        for (int e = 0; e < 4; ++e) {
            __half2 cc = pc_.h2[e];
            __half2 le = (e == 0) ? plf : pc_.h2[e - 1];
            float dx = __low2float(pu_.h2[e]) - __low2float(cc);
            dx = (gi > 0) ? dx : 0.f;
            float dy = __high2float(le) - __high2float(cc);
            dy = (gj + e > 0) ? dy : 0.f;
            o[e] = xv[e] - C_LAM * (dx + dy);
        }
        *(float4*)(out + (size_t)gi * WW + gj) = make_float4(o[0], o[1], o[2], o[3]);
    }
}

extern "C" void kernel_launch(void* const* d_in, const int* in_sizes, int n_in,
                              void* d_out, int out_size, void* d_ws, size_t ws_size,
                              hipStream_t stream)
{
    const float* x = (const float*)d_in[0];
    float* out = (float*)d_out;
    const size_t N = (size_t)HH * (size_t)WW;

    // ws layout: pA (64 MiB) | pB (64 MiB) | x_h (32 MiB)
    __half2* pA = (__half2*)d_ws;
    __half2* pB = pA + N;
    __half*  xh = (__half*)(pB + N);

    dim3 b1(BX, BY), g1(WW / TILE_W, HH / BY);
    dim3 b8(128),    g8(WW / TW8, HH / TH8);
    dim3 bL(256),    gL(WW / TW2, HH / TH2);

    tv_first<<<g1, b1, 0, stream>>>(x, pA, xh);              // iter 1
    __half2 *pin = pA, *pout = pB;
    for (int p = 0; p < 6; ++p) {                            // iters 2..49 (6x8)
        tv_iter8<<<g8, b8, 0, stream>>>(xh, pin, pout);
        __half2* t = pin; pin = pout; pout = t;
    }
    tv_last<<<gL, bL, 0, stream>>>(xh, x, pin, out);         // iter 50 + output
}

// Round 15
// 505.974 us; speedup vs baseline: 1.0240x; 1.0240x over previous
//
#include <hip/hip_runtime.h>
#include <hip/hip_fp16.h>

#define HH 4096
#define WW 4096

constexpr float C_LAM = 0.1f;   // ALPHA * LAMDA
constexpr float TAU_F = 0.25f;

// ---- first-iteration kernel geometry ----
#define BX 64
#define BY 8
#define VEC 4
#define TILE_W (BX * VEC)       // 256 cols per block

// ---- tv_last (2-ring) geometry ----
#define TW2 64
#define TH2 32
#define ERR 36
#define ECC 72
#define NCH (ECC / 4)
#define NSL (ERR * NCH)         // 648
#define LSZ (ERR * ECC)         // 2592

// ---- tv_iter8 (8-step, register-strip) geometry ----
// Each thread owns 4 rows x 8 px in REGISTERS. LDS holds only strip-boundary
// rows (px row3 / u row0) and packed chunk-edge columns (py7 / u0).
// R14 lesson: the FULLY-UNROLLED 8-iteration loop stretched live ranges ->
// ~190 total regs/wave (52 arch + ~140 AGPR), occupancy 33%, ~2x VALU from
// accvgpr moves. Fix: roll the outer loop (state/iter = 80 regs, fits arch).
#define TH8 32                  // interior rows
#define TW8 64                  // interior cols
#define XC8 80                  // extended cols [c0-8, c0+71]
#define NS8 12                  // 4-row strips over 48 extended rows
#define NQ8 10                  // 8-px chunks per row
#define NT8 120                 // active threads = NS8*NQ8

typedef float    __attribute__((ext_vector_type(4))) f32x4_t;
typedef float    __attribute__((ext_vector_type(2))) f32x2_t;
typedef unsigned __attribute__((ext_vector_type(2))) u32x2_t;

union H2x4 { float4 f4; f32x4_t v4; __half2 h2[4]; unsigned u32[4]; };
union H2x2 { float2 f2; f32x2_t v2; __half2 h2[2]; unsigned u32[2]; };
union H2U  { __half2 h; unsigned int u; };

__device__ __forceinline__ float clip1(float v) {
    return fminf(1.0f, fmaxf(-1.0f, v));
}

__device__ __forceinline__ unsigned h2u(__half2 h) { H2U a; a.h = h; return a.u; }
__device__ __forceinline__ __half2  u2h(unsigned u){ H2U a; a.u = u; return a.h; }

// v_perm_b32: result bytes select from {a(hi):b(lo)}; sel byte i in 0-3 -> b, 4-7 -> a
__device__ __forceinline__ __half2 permh(__half2 a, __half2 b, unsigned sel) {
    unsigned d;
    asm("v_perm_b32 %0, %1, %2, %3" : "=v"(d) : "v"(h2u(a)), "v"(h2u(b)), "v"(sel));
    return u2h(d);
}
__device__ __forceinline__ __half2 andh(__half2 v, unsigned m) { return u2h(h2u(v) & m); }

// packed clamp to [-1,1] (no __hmax2/__hmin2 in ROCm 7.2 headers)
__device__ __forceinline__ __half2 clamp1h2(__half2 v) {
    H2U a; a.h = v;
    unsigned int lo = 0xBC00BC00u;   // (-1, -1) fp16
    unsigned int hi = 0x3C003C00u;   // (+1, +1) fp16
    unsigned int t, r;
    asm("v_pk_max_f16 %0, %1, %2" : "=v"(t) : "v"(a.u), "v"(lo));
    asm("v_pk_min_f16 %0, %1, %2" : "=v"(r) : "v"(t),   "v"(hi));
    H2U b; b.u = r;
    return b.h;
}

__device__ __forceinline__ __half2 shfl_up_h2(__half2 v) {
    H2U a; a.h = v;
    int s = __shfl_up((int)a.u, 1, 64);
    H2U b; b.u = (unsigned)s;
    return b.h;
}

// (hi:lo) >> 16, as __half2: result = (lo.hi, hi.lo)
__device__ __forceinline__ __half2 align16(__half2 hi, __half2 lo) {
    H2U a, b, d;
    a.h = hi; b.h = lo;
    asm("v_alignbit_b32 %0, %1, %2, 16" : "=v"(d.u) : "v"(a.u), "v"(b.u));
    return d.h;
}

// iteration 0 (p=0 -> u=x):  p = clip(tau * grad(x)); also emits x_h = fp16(x)
__global__ __launch_bounds__(512) void tv_first(const float* __restrict__ x,
                                                __half2* __restrict__ po,
                                                __half* __restrict__ xh)
{
    const int tx = threadIdx.x, ty = threadIdx.y;
    const int i = blockIdx.y * BY + ty;
    const int j = blockIdx.x * TILE_W + tx * VEC;
    const size_t idx = (size_t)i * WW + j;

    float4 xc4 = *(const float4*)(x + idx);
    float4 xd4 = make_float4(0.f, 0.f, 0.f, 0.f);
    if (i < HH - 1) xd4 = *(const float4*)(x + idx + WW);

    float c[4] = {xc4.x, xc4.y, xc4.z, xc4.w};
    float d[4] = {xd4.x, xd4.y, xd4.z, xd4.w};

    float xr = __shfl_down(c[0], 1, 64);
    if (tx == BX - 1 && j + VEC < WW) xr = x[idx + VEC];

    H2x4 o;
#pragma unroll
    for (int e = 0; e < 4; ++e) {
        float gx = (i < HH - 1) ? (d[e] - c[e]) : 0.f;
        float rn = (e < 3) ? c[e + 1] : xr;
        float gy = (j + e < WW - 1) ? (rn - c[e]) : 0.f;
        o.h2[e] = __floats2half2_rn(clip1(TAU_F * gx), clip1(TAU_F * gy));
    }
    *(float4*)(po + idx) = o.f4;

    H2x2 xs;
    xs.h2[0] = __floats2half2_rn(c[0], c[1]);
    xs.h2[1] = __floats2half2_rn(c[2], c[3]);
    *(float2*)(xh + idx) = xs.f2;
}

// -------- eight fused Chambolle steps, register-strip decomposition --------
template<bool EDGE>
__device__ __forceinline__ void iter8_body(const __half* __restrict__ xh,
                                           const __half2* __restrict__ pi,
                                           __half2* __restrict__ po,
                                           __half* pxB, __half* uT,
                                           unsigned* pyE, unsigned* uE)
{
    const int tid = threadIdx.x;
    const bool act = (tid < NT8);
    const int t = act ? tid : (NT8 - 1);
    const int s = t / NQ8;
    const int q = t - s * NQ8;
    const int r0 = blockIdx.y * TH8, c0 = blockIdx.x * TW8;
    const int gi0 = r0 - 8 + 4 * s;              // global row of strip row 0
    const int gj0 = c0 - 8 + 8 * q;              // global col of chunk elem 0
    const int gjc = EDGE ? min(max(gj0, 0), WW - 8) : gj0;

    const int lB  = s * XC8 + 8 * q;             // own boundary-row slot
    const int lBu = ((s > 0) ? (s - 1) : 0) * XC8 + 8 * q;
    const int lBd = ((s < NS8 - 1) ? (s + 1) : s) * XC8 + 8 * q;
    const int eO = t * 2;                        // packed edge (u32 index)
    const int eL = ((q > 0) ? (t - 1) : t) * 2;
    const int eR = ((q < NQ8 - 1) ? (t + 1) : t) * 2;
    const bool wout = act && (s >= 2) && (s <= 9) && (q >= 1) && (q <= 8);

    unsigned mdy = 0xFFFFFFFFu, mgy = 0xFFFFFFFFu;
    if (EDGE) {
        if (gj0 == 0)      mdy = 0xFFFF0000u;    // zero dy at global col 0
        if (gj0 + 8 == WW) mgy = 0x0000FFFFu;    // zero gy at global col WW-1
    }

    const __half2 tau2 = __float2half2_rn(TAU_F);
    const __half2 nC2  = __float2half2_rn(-C_LAM);
    const unsigned SEL0 = 0x05040100u;   // (b.lo16, a.lo16)
    const unsigned SELH = 0x07060302u;   // (b.hi16, a.hi16)
    const unsigned SELM = 0x05040302u;   // (b.hi16, a.lo16)

    __half2 X[4][4], Y[4][4], XHr[4][4], U[4][4];

    // ---- stage A: load interleaved p + xh; deinterleave into registers ----
#pragma unroll
    for (int k = 0; k < 4; ++k) {
        int gik = gi0 + k;
        if (EDGE) gik = min(max(gik, 0), HH - 1);
        const size_t go = (size_t)gik * WW + gjc;
        H2x4 v0; v0.v4 = *(const f32x4_t*)(pi + go);
        H2x4 v1; v1.v4 = *(const f32x4_t*)(pi + go + 4);
        H2x4 xv; xv.v4 = *(const f32x4_t*)(xh + go);
        X[k][0] = permh(v0.h2[1], v0.h2[0], SEL0);
        Y[k][0] = permh(v0.h2[1], v0.h2[0], SELH);
        X[k][1] = permh(v0.h2[3], v0.h2[2], SEL0);
        Y[k][1] = permh(v0.h2[3], v0.h2[2], SELH);
        X[k][2] = permh(v1.h2[1], v1.h2[0], SEL0);
        Y[k][2] = permh(v1.h2[1], v1.h2[0], SELH);
        X[k][3] = permh(v1.h2[3], v1.h2[2], SEL0);
        Y[k][3] = permh(v1.h2[3], v1.h2[2], SELH);
#pragma unroll
        for (int m = 0; m < 4; ++m) XHr[k][m] = xv.h2[m];
    }

    auto publish = [&]() {
        if (act) {
            H2x4 w;
#pragma unroll
            for (int m = 0; m < 4; ++m) w.h2[m] = X[3][m];
            *(f32x4_t*)(pxB + lB) = w.v4;
            u32x2_t e;
            e.x = h2u(permh(Y[1][3], Y[0][3], SELH));   // (py7 r0, py7 r1)
            e.y = h2u(permh(Y[3][3], Y[2][3], SELH));   // (py7 r2, py7 r3)
            *(u32x2_t*)(pyE + eO) = e;
        }
    };

    auto ustage = [&]() {
        H2x4 pu; pu.v4 = *(const f32x4_t*)(pxB + lBu);
        u32x2_t Lp = *(const u32x2_t*)(pyE + eL);
        const __half2 L0 = u2h(Lp.x), L1 = u2h(Lp.y);
#pragma unroll
        for (int k = 0; k < 4; ++k) {
            __half2 dx[4], zm[4], dy[4];
#pragma unroll
            for (int m = 0; m < 4; ++m)
                dx[m] = __hsub2((k == 0) ? pu.h2[m] : X[k - 1][m], X[k][m]);
            if (EDGE && !(gi0 + k > 0)) {
#pragma unroll
                for (int m = 0; m < 4; ++m) dx[m] = u2h(0u);
            }
            zm[0] = (k == 0) ? permh(Y[k][0], L0, SEL0)
                  : (k == 1) ? permh(Y[k][0], L0, SELM)
                  : (k == 2) ? permh(Y[k][0], L1, SEL0)
                             : permh(Y[k][0], L1, SELM);
            zm[1] = align16(Y[k][1], Y[k][0]);
            zm[2] = align16(Y[k][2], Y[k][1]);
            zm[3] = align16(Y[k][3], Y[k][2]);
#pragma unroll
            for (int m = 0; m < 4; ++m) dy[m] = __hsub2(zm[m], Y[k][m]);
            if (EDGE) dy[0] = andh(dy[0], mdy);
#pragma unroll
            for (int m = 0; m < 4; ++m)
                U[k][m] = __hfma2(__hadd2(dx[m], dy[m]), nC2, XHr[k][m]);
        }
        if (act) {
            H2x4 w;
#pragma unroll
            for (int m = 0; m < 4; ++m) w.h2[m] = U[0][m];
            *(f32x4_t*)(uT + lB) = w.v4;
            u32x2_t e;
            e.x = h2u(permh(U[1][0], U[0][0], SEL0));   // (u0 r0, u0 r1)
            e.y = h2u(permh(U[3][0], U[2][0], SEL0));   // (u0 r2, u0 r3)
            *(u32x2_t*)(uE + eO) = e;
        }
    };

    auto pstage = [&]() {
        H2x4 ud; ud.v4 = *(const f32x4_t*)(uT + lBd);
        u32x2_t Rp = *(const u32x2_t*)(uE + eR);
        const __half2 R0 = u2h(Rp.x), R1 = u2h(Rp.y);
#pragma unroll
        for (int k = 0; k < 4; ++k) {
            __half2 gx[4], zp[4], gy[4];
#pragma unroll
            for (int m = 0; m < 4; ++m)
                gx[m] = __hsub2((k == 3) ? ud.h2[m] : U[k + 1][m], U[k][m]);
            if (EDGE && !(gi0 + k < HH - 1)) {
#pragma unroll
                for (int m = 0; m < 4; ++m) gx[m] = u2h(0u);
            }
            zp[0] = align16(U[k][1], U[k][0]);
            zp[1] = align16(U[k][2], U[k][1]);
            zp[2] = align16(U[k][3], U[k][2]);
            zp[3] = (k == 0) ? permh(R0, U[k][3], SELM)   // (u7, uR0 r0)
                  : (k == 1) ? permh(R0, U[k][3], SELH)
                  : (k == 2) ? permh(R1, U[k][3], SELM)
                             : permh(R1, U[k][3], SELH);
#pragma unroll
            for (int m = 0; m < 4; ++m) gy[m] = __hsub2(zp[m], U[k][m]);
            if (EDGE) gy[3] = andh(gy[3], mgy);
#pragma unroll
            for (int m = 0; m < 4; ++m) {
                X[k][m] = clamp1h2(__hfma2(gx[m], tau2, X[k][m]));
                Y[k][m] = clamp1h2(__hfma2(gy[m], tau2, Y[k][m]));
            }
        }
    };

    // ROLLED outer loop (see header comment): 7 LDS iterations...
#pragma unroll 1
    for (int it = 0; it < 7; ++it) {
        publish(); __syncthreads();
        ustage();  __syncthreads();
        pstage();
    }
    // ...then the peeled final iteration, writing p to global.
    publish(); __syncthreads();
    ustage();  __syncthreads();
    pstage();

    if (wout) {
#pragma unroll
        for (int k = 0; k < 4; ++k) {
            const size_t go = (size_t)(gi0 + k) * WW + gj0;
            H2x4 w0, w1;
            w0.h2[0] = permh(Y[k][0], X[k][0], SEL0);   // (px0, py0)
            w0.h2[1] = permh(Y[k][0], X[k][0], SELH);   // (px1, py1)
            w0.h2[2] = permh(Y[k][1], X[k][1], SEL0);
            w0.h2[3] = permh(Y[k][1], X[k][1], SELH);
            w1.h2[0] = permh(Y[k][2], X[k][2], SEL0);
            w1.h2[1] = permh(Y[k][2], X[k][2], SELH);
            w1.h2[2] = permh(Y[k][3], X[k][3], SEL0);
            w1.h2[3] = permh(Y[k][3], X[k][3], SELH);
            *(f32x4_t*)(po + go)     = w0.v4;
            *(f32x4_t*)(po + go + 4) = w1.v4;
        }
    }
}

__global__ __launch_bounds__(128, 4) void tv_iter8(const __half* __restrict__ xh,
                                                   const __half2* __restrict__ pi,
                                                   __half2* __restrict__ po)
{
    __shared__ __align__(16) __half   pxB[NS8 * XC8];
    __shared__ __align__(16) __half   uT [NS8 * XC8];
    __shared__ __align__(8)  unsigned pyE[NT8 * 2];
    __shared__ __align__(8)  unsigned uE [NT8 * 2];

    const bool edge = (blockIdx.x == 0) || (blockIdx.x == gridDim.x - 1) ||
                      (blockIdx.y == 0) || (blockIdx.y == gridDim.y - 1);
    if (!edge) iter8_body<false>(xh, pi, po, pxB, uT, pyE, uE);
    else       iter8_body<true >(xh, pi, po, pxB, uT, pyE, uE);
}

// -------- final: one more p-update (p49 -> p50) fused with the output --------
__global__ __launch_bounds__(256) void tv_last(const __half* __restrict__ xh,
                                               const float* __restrict__ x,
                                               const __half2* __restrict__ pi,
                                               float* __restrict__ out)
{
    __shared__ __half2 sp0[LSZ];
    __shared__ __half2 sp1[LSZ];
    __shared__ float   su [LSZ];

    const int tid  = threadIdx.x;
    const int lane = tid & 63;
    const int r0 = blockIdx.y * TH2;
    const int c0 = blockIdx.x * TW2;
    const __half2 tau2 = __float2half2_rn(TAU_F);

    int lb[3], lup[3], llf[3], ldn[3], lrt[3], gj0a[3], gofs[3];
    bool wr[3];
#pragma unroll
    for (int r = 0; r < 3; ++r) {
        int slot = tid + 256 * r;
        wr[r] = (slot < NSL);
        if (slot >= NSL) slot = NSL - 1;
        int cr = slot / NCH;
        int cc = slot - cr * NCH;
        int gi  = r0 - 2 + cr;
        int gj0 = c0 - 4 + cc * 4;
        int gic = min(max(gi, 0), HH - 1);
        int gjc = min(max(gj0, 0), WW - 4);
        gofs[r] = gic * WW + gjc;
        int l   = cr * ECC + cc * 4;
        lb[r]  = l;
        lup[r] = (cr > 0) ? l - ECC : l;
        llf[r] = (l > 0) ? l - 1 : 0;
        ldn[r] = (cr < ERR - 1) ? l + ECC : l;
        lrt[r] = min(l + 4, LSZ - 1);
        gj0a[r] = gj0;
    }

    __half2 c2[3][4];
    H2x2    xc[3];
#pragma unroll
    for (int r = 0; r < 3; ++r) {
        H2x4 v; v.f4 = *(const float4*)(pi + gofs[r]);
        xc[r].f2    = *(const float2*)(xh + gofs[r]);
        if (wr[r]) *(float4*)&sp0[lb[r]] = v.f4;
        c2[r][0] = v.h2[0]; c2[r][1] = v.h2[1];
        c2[r][2] = v.h2[2]; c2[r][3] = v.h2[3];
    }
    __syncthreads();

    float u1v[3][4];
#pragma unroll
    for (int r = 0; r < 3; ++r) {
        H2x4 up; up.f4 = *(float4*)&sp0[lup[r]];
        __half2 lf = shfl_up_h2(c2[r][3]);
        if (lane == 0) lf = sp0[llf[r]];
        float xs[4] = {__low2float(xc[r].h2[0]), __high2float(xc[r].h2[0]),
                       __low2float(xc[r].h2[1]), __high2float(xc[r].h2[1])};
        float4 w;
        float* wp = &w.x;
#pragma unroll
        for (int e = 0; e < 4; ++e) {
            __half2 cc = c2[r][e];
            __half2 le = (e == 0) ? lf : c2[r][e - 1];
            float dx = __low2float(up.h2[e]) - __low2float(cc);
            float dy = __high2float(le) - __high2float(cc);
            dy = (gj0a[r] + e > 0) ? dy : 0.f;
            float u = xs[e] - C_LAM * (dx + dy);
            u1v[r][e] = u;
            wp[e] = u;
        }
        if (wr[r]) *(float4*)&su[lb[r]] = w;
    }
    __syncthreads();

#pragma unroll
    for (int r = 0; r < 3; ++r) {
        float4 dn4 = *(float4*)&su[ldn[r]];
        float urr = __shfl_down(u1v[r][0], 1, 64);
        if (lane == 63) urr = su[lrt[r]];
        float dn[4] = {dn4.x, dn4.y, dn4.z, dn4.w};
        H2x4 w;
#pragma unroll
        for (int e = 0; e < 4; ++e) {
            float uc = u1v[r][e];
            float gx = dn[e] - uc;
            float rt = (e == 3) ? urr : u1v[r][e + 1];
            float gy = (gj0a[r] + e < WW - 1) ? (rt - uc) : 0.f;
            __half2 g = __float22half2_rn(make_float2(gx, gy));
            w.h2[e] = clamp1h2(__hfma2(g, tau2, c2[r][e]));
        }
        if (wr[r]) *(float4*)&sp1[lb[r]] = w.f4;
    }
    __syncthreads();

    // out = x - c*div(p50) on interior
#pragma unroll
    for (int r = 0; r < 2; ++r) {
        int slot = tid + 256 * r;
        int ir = slot >> 4, icc = slot & 15;
        int er = ir + 2, ec = icc * 4 + 4;
        int l  = er * ECC + ec;
        int gi = r0 + ir, gj = c0 + icc * 4;

        H2x4 pc_; pc_.f4 = *(float4*)&sp1[l];
        H2x4 pu_; pu_.f4 = *(float4*)&sp1[l - ECC];
        __half2 plf = shfl_up_h2(pc_.h2[3]);
        if ((tid & 15) == 0) plf = sp1[l - 1];

        float4 xr4 = *(const float4*)(x + (size_t)gi * WW + gj);
        float xv[4] = {xr4.x, xr4.y, xr4.z, xr4.w};
        float o[4];
#pragma unroll
        for (int e = 0; e < 4; ++e) {
            __half2 cc = pc_.h2[e];
            __half2 le = (e == 0) ? plf : pc_.h2[e - 1];
            float dx = __low2float(pu_.h2[e]) - __low2float(cc);
            dx = (gi > 0) ? dx : 0.f;
            float dy = __high2float(le) - __high2float(cc);
            dy = (gj + e > 0) ? dy : 0.f;
            o[e] = xv[e] - C_LAM * (dx + dy);
        }
        *(float4*)(out + (size_t)gi * WW + gj) = make_float4(o[0], o[1], o[2], o[3]);
    }
}

extern "C" void kernel_launch(void* const* d_in, const int* in_sizes, int n_in,
                              void* d_out, int out_size, void* d_ws, size_t ws_size,
                              hipStream_t stream)
{
    const float* x = (const float*)d_in[0];
    float* out = (float*)d_out;
    const size_t N = (size_t)HH * (size_t)WW;

    // ws layout: pA (64 MiB) | pB (64 MiB) | x_h (32 MiB)
    __half2* pA = (__half2*)d_ws;
    __half2* pB = pA + N;
    __half*  xh = (__half*)(pB + N);

    dim3 b1(BX, BY), g1(WW / TILE_W, HH / BY);
    dim3 b8(128),    g8(WW / TW8, HH / TH8);
    dim3 bL(256),    gL(WW / TW2, HH / TH2);

    tv_first<<<g1, b1, 0, stream>>>(x, pA, xh);              // iter 1
    __half2 *pin = pA, *pout = pB;
    for (int p = 0; p < 6; ++p) {                            // iters 2..49 (6x8)
        tv_iter8<<<g8, b8, 0, stream>>>(xh, pin, pout);
        __half2* t = pin; pin = pout; pout = t;
    }
    tv_last<<<gL, bL, 0, stream>>>(xh, x, pin, out);         // iter 50 + output
}

// Round 16
// 476.307 us; speedup vs baseline: 1.0878x; 1.0623x over previous
//
#include <hip/hip_runtime.h>
#include <hip/hip_fp16.h>

#define HH 4096
#define WW 4096

constexpr float C_LAM = 0.1f;   // ALPHA * LAMDA
constexpr float TAU_F = 0.25f;

// ---- first-iteration kernel geometry ----
#define BX 64
#define BY 8
#define VEC 4
#define TILE_W (BX * VEC)       // 256 cols per block

// ---- tv_last (2-ring) geometry ----
#define TW2 64
#define TH2 32
#define ERR 36
#define ECC 72
#define NCH (ECC / 4)
#define NSL (ERR * NCH)         // 648
#define LSZ (ERR * ECC)         // 2592

// ---- tv_iter8 (8-step, register-strip v2) geometry ----
// R13-R15 lesson: 4-row strips need ~100 live regs; the allocator targets a
// 64-VGPR arch budget regardless of launch bounds and spills ~130 regs to
// AGPRs (v_accvgpr copies ~doubled VALU, occupancy 34%). Fix: HALVE the
// state. 2-row x 8-px strips: X/Y/XH/U = 32 regs + temps ~= 60 -> fits 64.
#define TH8 32                  // interior rows
#define TW8 64                  // interior cols
#define XC8 80                  // extended cols [c0-8, c0+71]
#define NS8 24                  // 2-row strips over 48 extended rows
#define NQ8 10                  // 8-px chunks per row
#define NT8 240                 // active threads = NS8*NQ8

typedef float    __attribute__((ext_vector_type(4))) f32x4_t;
typedef float    __attribute__((ext_vector_type(2))) f32x2_t;

union H2x4 { float4 f4; f32x4_t v4; __half2 h2[4]; unsigned u32[4]; };
union H2x2 { float2 f2; f32x2_t v2; __half2 h2[2]; unsigned u32[2]; };
union H2U  { __half2 h; unsigned int u; };

__device__ __forceinline__ float clip1(float v) {
    return fminf(1.0f, fmaxf(-1.0f, v));
}

__device__ __forceinline__ unsigned h2u(__half2 h) { H2U a; a.h = h; return a.u; }
__device__ __forceinline__ __half2  u2h(unsigned u){ H2U a; a.u = u; return a.h; }

// v_perm_b32: result bytes select from {a(hi):b(lo)}; sel byte i in 0-3 -> b, 4-7 -> a
__device__ __forceinline__ __half2 permh(__half2 a, __half2 b, unsigned sel) {
    unsigned d;
    asm("v_perm_b32 %0, %1, %2, %3" : "=v"(d) : "v"(h2u(a)), "v"(h2u(b)), "v"(sel));
    return u2h(d);
}
__device__ __forceinline__ __half2 andh(__half2 v, unsigned m) { return u2h(h2u(v) & m); }

// packed clamp to [-1,1] (no __hmax2/__hmin2 in ROCm 7.2 headers)
__device__ __forceinline__ __half2 clamp1h2(__half2 v) {
    H2U a; a.h = v;
    unsigned int lo = 0xBC00BC00u;   // (-1, -1) fp16
    unsigned int hi = 0x3C003C00u;   // (+1, +1) fp16
    unsigned int t, r;
    asm("v_pk_max_f16 %0, %1, %2" : "=v"(t) : "v"(a.u), "v"(lo));
    asm("v_pk_min_f16 %0, %1, %2" : "=v"(r) : "v"(t),   "v"(hi));
    H2U b; b.u = r;
    return b.h;
}

__device__ __forceinline__ __half2 shfl_up_h2(__half2 v) {
    H2U a; a.h = v;
    int s = __shfl_up((int)a.u, 1, 64);
    H2U b; b.u = (unsigned)s;
    return b.h;
}

// (hi:lo) >> 16, as __half2: result = (lo.hi, hi.lo)
__device__ __forceinline__ __half2 align16(__half2 hi, __half2 lo) {
    H2U a, b, d;
    a.h = hi; b.h = lo;
    asm("v_alignbit_b32 %0, %1, %2, 16" : "=v"(d.u) : "v"(a.u), "v"(b.u));
    return d.h;
}

// iteration 0 (p=0 -> u=x):  p = clip(tau * grad(x)); also emits x_h = fp16(x)
__global__ __launch_bounds__(512) void tv_first(const float* __restrict__ x,
                                                __half2* __restrict__ po,
                                                __half* __restrict__ xh)
{
    const int tx = threadIdx.x, ty = threadIdx.y;
    const int i = blockIdx.y * BY + ty;
    const int j = blockIdx.x * TILE_W + tx * VEC;
    const size_t idx = (size_t)i * WW + j;

    float4 xc4 = *(const float4*)(x + idx);
    float4 xd4 = make_float4(0.f, 0.f, 0.f, 0.f);
    if (i < HH - 1) xd4 = *(const float4*)(x + idx + WW);

    float c[4] = {xc4.x, xc4.y, xc4.z, xc4.w};
    float d[4] = {xd4.x, xd4.y, xd4.z, xd4.w};

    float xr = __shfl_down(c[0], 1, 64);
    if (tx == BX - 1 && j + VEC < WW) xr = x[idx + VEC];

    H2x4 o;
#pragma unroll
    for (int e = 0; e < 4; ++e) {
        float gx = (i < HH - 1) ? (d[e] - c[e]) : 0.f;
        float rn = (e < 3) ? c[e + 1] : xr;
        float gy = (j + e < WW - 1) ? (rn - c[e]) : 0.f;
        o.h2[e] = __floats2half2_rn(clip1(TAU_F * gx), clip1(TAU_F * gy));
    }
    *(float4*)(po + idx) = o.f4;

    H2x2 xs;
    xs.h2[0] = __floats2half2_rn(c[0], c[1]);
    xs.h2[1] = __floats2half2_rn(c[2], c[3]);
    *(float2*)(xh + idx) = xs.f2;
}

// -------- eight fused Chambolle steps, 2-row register strips --------
template<bool EDGE>
__device__ __forceinline__ void iter8_body(const __half* __restrict__ xh,
                                           const __half2* __restrict__ pi,
                                           __half2* __restrict__ po,
                                           __half* pxB, __half* uT,
                                           unsigned* pyE, unsigned* uE)
{
    const int tid = threadIdx.x;
    const bool act = (tid < NT8);
    const int t = act ? tid : (NT8 - 1);
    const int s = t / NQ8;
    const int q = t - s * NQ8;
    const int r0 = blockIdx.y * TH8, c0 = blockIdx.x * TW8;
    const int gi0 = r0 - 8 + 2 * s;              // global row of strip row 0
    const int gj0 = c0 - 8 + 8 * q;              // global col of chunk elem 0
    const int gjc = EDGE ? min(max(gj0, 0), WW - 8) : gj0;

    const int lB  = s * XC8 + 8 * q;             // own boundary-row slot
    const int lBu = ((s > 0) ? (s - 1) : 0) * XC8 + 8 * q;
    const int lBd = ((s < NS8 - 1) ? (s + 1) : s) * XC8 + 8 * q;
    const int eO = t;                            // packed edge (u32 index)
    const int eL = (q > 0) ? (t - 1) : t;
    const int eR = (q < NQ8 - 1) ? (t + 1) : t;
    const bool wout = act && (s >= 4) && (s < 20) && (q >= 1) && (q <= 8);

    unsigned mdy = 0xFFFFFFFFu, mgy = 0xFFFFFFFFu;
    if (EDGE) {
        if (gj0 == 0)      mdy = 0xFFFF0000u;    // zero dy at global col 0
        if (gj0 + 8 == WW) mgy = 0x0000FFFFu;    // zero gy at global col WW-1
    }

    const __half2 tau2 = __float2half2_rn(TAU_F);
    const __half2 nC2  = __float2half2_rn(-C_LAM);
    const unsigned SEL0 = 0x05040100u;   // (a.lo16, b.lo16)
    const unsigned SELH = 0x07060302u;   // (a.hi16, b.hi16)
    const unsigned SELM = 0x05040302u;   // (a.lo16, b.hi16)

    __half2 X[2][4], Y[2][4], XHr[2][4], U[2][4];

    // ---- stage A: load interleaved p + xh; deinterleave into registers ----
#pragma unroll
    for (int k = 0; k < 2; ++k) {
        int gik = gi0 + k;
        if (EDGE) gik = min(max(gik, 0), HH - 1);
        const size_t go = (size_t)gik * WW + gjc;
        H2x4 v0; v0.v4 = *(const f32x4_t*)(pi + go);
        H2x4 v1; v1.v4 = *(const f32x4_t*)(pi + go + 4);
        H2x4 xv; xv.v4 = *(const f32x4_t*)(xh + go);
        X[k][0] = permh(v0.h2[1], v0.h2[0], SEL0);
        Y[k][0] = permh(v0.h2[1], v0.h2[0], SELH);
        X[k][1] = permh(v0.h2[3], v0.h2[2], SEL0);
        Y[k][1] = permh(v0.h2[3], v0.h2[2], SELH);
        X[k][2] = permh(v1.h2[1], v1.h2[0], SEL0);
        Y[k][2] = permh(v1.h2[1], v1.h2[0], SELH);
        X[k][3] = permh(v1.h2[3], v1.h2[2], SEL0);
        Y[k][3] = permh(v1.h2[3], v1.h2[2], SELH);
#pragma unroll
        for (int m = 0; m < 4; ++m) XHr[k][m] = xv.h2[m];
    }

    auto publish = [&]() {
        if (act) {
            H2x4 w;
#pragma unroll
            for (int m = 0; m < 4; ++m) w.h2[m] = X[1][m];
            *(f32x4_t*)(pxB + lB) = w.v4;
            pyE[eO] = h2u(permh(Y[1][3], Y[0][3], SELH));  // (py7 r0, py7 r1)
        }
    };

    auto ustage = [&]() {
        H2x4 pu; pu.v4 = *(const f32x4_t*)(pxB + lBu);
        const __half2 L = u2h(pyE[eL]);
#pragma unroll
        for (int k = 0; k < 2; ++k) {
            __half2 dx[4], zm[4], dy[4];
#pragma unroll
            for (int m = 0; m < 4; ++m)
                dx[m] = __hsub2((k == 0) ? pu.h2[m] : X[0][m], X[k][m]);
            if (EDGE && !(gi0 + k > 0)) {
#pragma unroll
                for (int m = 0; m < 4; ++m) dx[m] = u2h(0u);
            }
            zm[0] = (k == 0) ? permh(Y[k][0], L, SEL0)
                             : permh(Y[k][0], L, SELM);
            zm[1] = align16(Y[k][1], Y[k][0]);
            zm[2] = align16(Y[k][2], Y[k][1]);
            zm[3] = align16(Y[k][3], Y[k][2]);
#pragma unroll
            for (int m = 0; m < 4; ++m) dy[m] = __hsub2(zm[m], Y[k][m]);
            if (EDGE) dy[0] = andh(dy[0], mdy);
#pragma unroll
            for (int m = 0; m < 4; ++m)
                U[k][m] = __hfma2(__hadd2(dx[m], dy[m]), nC2, XHr[k][m]);
        }
        if (act) {
            H2x4 w;
#pragma unroll
            for (int m = 0; m < 4; ++m) w.h2[m] = U[0][m];
            *(f32x4_t*)(uT + lB) = w.v4;
            uE[eO] = h2u(permh(U[1][0], U[0][0], SEL0));   // (u0 r0, u0 r1)
        }
    };

    auto pstage = [&]() {
        H2x4 ud; ud.v4 = *(const f32x4_t*)(uT + lBd);
        const __half2 R = u2h(uE[eR]);
#pragma unroll
        for (int k = 0; k < 2; ++k) {
            __half2 gx[4], zp[4], gy[4];
#pragma unroll
            for (int m = 0; m < 4; ++m)
                gx[m] = __hsub2((k == 1) ? ud.h2[m] : U[1][m], U[k][m]);
            if (EDGE && !(gi0 + k < HH - 1)) {
#pragma unroll
                for (int m = 0; m < 4; ++m) gx[m] = u2h(0u);
            }
            zp[0] = align16(U[k][1], U[k][0]);
            zp[1] = align16(U[k][2], U[k][1]);
            zp[2] = align16(U[k][3], U[k][2]);
            zp[3] = (k == 0) ? permh(R, U[k][3], SELM)     // (u7, uR0 r0)
                             : permh(R, U[k][3], SELH);    // (u7, uR0 r1)
#pragma unroll
            for (int m = 0; m < 4; ++m) gy[m] = __hsub2(zp[m], U[k][m]);
            if (EDGE) gy[3] = andh(gy[3], mgy);
#pragma unroll
            for (int m = 0; m < 4; ++m) {
                X[k][m] = clamp1h2(__hfma2(gx[m], tau2, X[k][m]));
                Y[k][m] = clamp1h2(__hfma2(gy[m], tau2, Y[k][m]));
            }
        }
    };

    // rolled outer loop keeps one iteration's state live at a time
#pragma unroll 1
    for (int it = 0; it < 7; ++it) {
        publish(); __syncthreads();
        ustage();  __syncthreads();
        pstage();
    }
    // peeled final iteration, then global write of p
    publish(); __syncthreads();
    ustage();  __syncthreads();
    pstage();

    if (wout) {
#pragma unroll
        for (int k = 0; k < 2; ++k) {
            const size_t go = (size_t)(gi0 + k) * WW + gj0;
            H2x4 w0, w1;
            w0.h2[0] = permh(Y[k][0], X[k][0], SEL0);   // (px0, py0)
            w0.h2[1] = permh(Y[k][0], X[k][0], SELH);   // (px1, py1)
            w0.h2[2] = permh(Y[k][1], X[k][1], SEL0);
            w0.h2[3] = permh(Y[k][1], X[k][1], SELH);
            w1.h2[0] = permh(Y[k][2], X[k][2], SEL0);
            w1.h2[1] = permh(Y[k][2], X[k][2], SELH);
            w1.h2[2] = permh(Y[k][3], X[k][3], SEL0);
            w1.h2[3] = permh(Y[k][3], X[k][3], SELH);
            *(f32x4_t*)(po + go)     = w0.v4;
            *(f32x4_t*)(po + go + 4) = w1.v4;
        }
    }
}

__global__ __launch_bounds__(256) void tv_iter8(const __half* __restrict__ xh,
                                                const __half2* __restrict__ pi,
                                                __half2* __restrict__ po)
{
    __shared__ __align__(16) __half   pxB[NS8 * XC8];
    __shared__ __align__(16) __half   uT [NS8 * XC8];
    __shared__ __align__(8)  unsigned pyE[NT8];
    __shared__ __align__(8)  unsigned uE [NT8];

    const bool edge = (blockIdx.x == 0) || (blockIdx.x == gridDim.x - 1) ||
                      (blockIdx.y == 0) || (blockIdx.y == gridDim.y - 1);
    if (!edge) iter8_body<false>(xh, pi, po, pxB, uT, pyE, uE);
    else       iter8_body<true >(xh, pi, po, pxB, uT, pyE, uE);
}

// -------- final: one more p-update (p49 -> p50) fused with the output --------
__global__ __launch_bounds__(256) void tv_last(const __half* __restrict__ xh,
                                               const float* __restrict__ x,
                                               const __half2* __restrict__ pi,
                                               float* __restrict__ out)
{
    __shared__ __half2 sp0[LSZ];
    __shared__ __half2 sp1[LSZ];
    __shared__ float   su [LSZ];

    const int tid  = threadIdx.x;
    const int lane = tid & 63;
    const int r0 = blockIdx.y * TH2;
    const int c0 = blockIdx.x * TW2;
    const __half2 tau2 = __float2half2_rn(TAU_F);

    int lb[3], lup[3], llf[3], ldn[3], lrt[3], gj0a[3], gofs[3];
    bool wr[3];
#pragma unroll
    for (int r = 0; r < 3; ++r) {
        int slot = tid + 256 * r;
        wr[r] = (slot < NSL);
        if (slot >= NSL) slot = NSL - 1;
        int cr = slot / NCH;
        int cc = slot - cr * NCH;
        int gi  = r0 - 2 + cr;
        int gj0 = c0 - 4 + cc * 4;
        int gic = min(max(gi, 0), HH - 1);
        int gjc = min(max(gj0, 0), WW - 4);
        gofs[r] = gic * WW + gjc;
        int l   = cr * ECC + cc * 4;
        lb[r]  = l;
        lup[r] = (cr > 0) ? l - ECC : l;
        llf[r] = (l > 0) ? l - 1 : 0;
        ldn[r] = (cr < ERR - 1) ? l + ECC : l;
        lrt[r] = min(l + 4, LSZ - 1);
        gj0a[r] = gj0;
    }

    __half2 c2[3][4];
    H2x2    xc[3];
#pragma unroll
    for (int r = 0; r < 3; ++r) {
        H2x4 v; v.f4 = *(const float4*)(pi + gofs[r]);
        xc[r].f2    = *(const float2*)(xh + gofs[r]);
        if (wr[r]) *(float4*)&sp0[lb[r]] = v.f4;
        c2[r][0] = v.h2[0]; c2[r][1] = v.h2[1];
        c2[r][2] = v.h2[2]; c2[r][3] = v.h2[3];
    }
    __syncthreads();

    float u1v[3][4];
#pragma unroll
    for (int r = 0; r < 3; ++r) {
        H2x4 up; up.f4 = *(float4*)&sp0[lup[r]];
        __half2 lf = shfl_up_h2(c2[r][3]);
        if (lane == 0) lf = sp0[llf[r]];
        float xs[4] = {__low2float(xc[r].h2[0]), __high2float(xc[r].h2[0]),
                       __low2float(xc[r].h2[1]), __high2float(xc[r].h2[1])};
        float4 w;
        float* wp = &w.x;
#pragma unroll
        for (int e = 0; e < 4; ++e) {
            __half2 cc = c2[r][e];
            __half2 le = (e == 0) ? lf : c2[r][e - 1];
            float dx = __low2float(up.h2[e]) - __low2float(cc);
            float dy = __high2float(le) - __high2float(cc);
            dy = (gj0a[r] + e > 0) ? dy : 0.f;
            float u = xs[e] - C_LAM * (dx + dy);
            u1v[r][e] = u;
            wp[e] = u;
        }
        if (wr[r]) *(float4*)&su[lb[r]] = w;
    }
    __syncthreads();

#pragma unroll
    for (int r = 0; r < 3; ++r) {
        float4 dn4 = *(float4*)&su[ldn[r]];
        float urr = __shfl_down(u1v[r][0], 1, 64);
        if (lane == 63) urr = su[lrt[r]];
        float dn[4] = {dn4.x, dn4.y, dn4.z, dn4.w};
        H2x4 w;
#pragma unroll
        for (int e = 0; e < 4; ++e) {
            float uc = u1v[r][e];
            float gx = dn[e] - uc;
            float rt = (e == 3) ? urr : u1v[r][e + 1];
            float gy = (gj0a[r] + e < WW - 1) ? (rt - uc) : 0.f;
            __half2 g = __float22half2_rn(make_float2(gx, gy));
            w.h2[e] = clamp1h2(__hfma2(g, tau2, c2[r][e]));
        }
        if (wr[r]) *(float4*)&sp1[lb[r]] = w.f4;
    }
    __syncthreads();

    // out = x - c*div(p50) on interior
#pragma unroll
    for (int r = 0; r < 2; ++r) {
        int slot = tid + 256 * r;
        int ir = slot >> 4, icc = slot & 15;
        int er = ir + 2, ec = icc * 4 + 4;
        int l  = er * ECC + ec;
        int gi = r0 + ir, gj = c0 + icc * 4;

        H2x4 pc_; pc_.f4 = *(float4*)&sp1[l];
        H2x4 pu_; pu_.f4 = *(float4*)&sp1[l - ECC];
        __half2 plf = shfl_up_h2(pc_.h2[3]);
        if ((tid & 15) == 0) plf = sp1[l - 1];

        float4 xr4 = *(const float4*)(x + (size_t)gi * WW + gj);
        float xv[4] = {xr4.x, xr4.y, xr4.z, xr4.w};
        float o[4];
#pragma unroll
        for (int e = 0; e < 4; ++e) {
            __half2 cc = pc_.h2[e];
            __half2 le = (e == 0) ? plf : pc_.h2[e - 1];
            float dx = __low2float(pu_.h2[e]) - __low2float(cc);
            dx = (gi > 0) ? dx : 0.f;
            float dy = __high2float(le) - __high2float(cc);
            dy = (gj + e > 0) ? dy : 0.f;
            o[e] = xv[e] - C_LAM * (dx + dy);
        }
        *(float4*)(out + (size_t)gi * WW + gj) = make_float4(o[0], o[1], o[2], o[3]);
    }
}

extern "C" void kernel_launch(void* const* d_in, const int* in_sizes, int n_in,
                              void* d_out, int out_size, void* d_ws, size_t ws_size,
                              hipStream_t stream)
{
    const float* x = (const float*)d_in[0];
    float* out = (float*)d_out;
    const size_t N = (size_t)HH * (size_t)WW;

    // ws layout: pA (64 MiB) | pB (64 MiB) | x_h (32 MiB)
    __half2* pA = (__half2*)d_ws;
    __half2* pB = pA + N;
    __half*  xh = (__half*)(pB + N);

    dim3 b1(BX, BY), g1(WW / TILE_W, HH / BY);
    dim3 b8(256),    g8(WW / TW8, HH / TH8);
    dim3 bL(256),    gL(WW / TW2, HH / TH2);

    tv_first<<<g1, b1, 0, stream>>>(x, pA, xh);              // iter 1
    __half2 *pin = pA, *pout = pB;
    for (int p = 0; p < 6; ++p) {                            // iters 2..49 (6x8)
        tv_iter8<<<g8, b8, 0, stream>>>(xh, pin, pout);
        __half2* t = pin; pin = pout; pout = t;
    }
    tv_last<<<gL, bL, 0, stream>>>(xh, x, pin, out);         // iter 50 + output
}

// Round 17
// 475.640 us; speedup vs baseline: 1.0893x; 1.0014x over previous
//
#include <hip/hip_runtime.h>
#include <hip/hip_fp16.h>

#define HH 4096
#define WW 4096

constexpr float C_LAM = 0.1f;   // ALPHA * LAMDA
constexpr float TAU_F = 0.25f;

// ---- first-iteration kernel geometry ----
#define BX 64
#define BY 8
#define VEC 4
#define TILE_W (BX * VEC)       // 256 cols per block

// ---- tv_last (2-ring) geometry ----
#define TW2 64
#define TH2 32
#define ERR 36
#define ECC 72
#define NCH (ECC / 4)
#define NSL (ERR * NCH)         // 648
#define LSZ (ERR * ECC)         // 2592

// ---- tv_iter8 (8-step, register-strip v3) geometry ----
// 2-row x 8-px strips in registers (R16). v3: state kept in H2x4 UNIONS so
// every b128 LDS/global access consumes the state quad directly -- no
// repack v_movs before ds_write_b128, fewer rolled-loop phi copies.
#define TH8 32                  // interior rows
#define TW8 64                  // interior cols
#define XC8 80                  // extended cols [c0-8, c0+71]
#define NS8 24                  // 2-row strips over 48 extended rows
#define NQ8 10                  // 8-px chunks per row
#define NT8 240                 // active threads = NS8*NQ8

typedef float    __attribute__((ext_vector_type(4))) f32x4_t;
typedef float    __attribute__((ext_vector_type(2))) f32x2_t;

union H2x4 { float4 f4; f32x4_t v4; __half2 h2[4]; unsigned u32[4]; };
union H2x2 { float2 f2; f32x2_t v2; __half2 h2[2]; unsigned u32[2]; };
union H2U  { __half2 h; unsigned int u; };

__device__ __forceinline__ float clip1(float v) {
    return fminf(1.0f, fmaxf(-1.0f, v));
}

__device__ __forceinline__ unsigned h2u(__half2 h) { H2U a; a.h = h; return a.u; }
__device__ __forceinline__ __half2  u2h(unsigned u){ H2U a; a.u = u; return a.h; }

// v_perm_b32: result bytes select from {a(hi):b(lo)}; sel byte i in 0-3 -> b, 4-7 -> a
__device__ __forceinline__ __half2 permh(__half2 a, __half2 b, unsigned sel) {
    unsigned d;
    asm("v_perm_b32 %0, %1, %2, %3" : "=v"(d) : "v"(h2u(a)), "v"(h2u(b)), "v"(sel));
    return u2h(d);
}
__device__ __forceinline__ __half2 andh(__half2 v, unsigned m) { return u2h(h2u(v) & m); }

// packed clamp to [-1,1] (no __hmax2/__hmin2 in ROCm 7.2 headers)
__device__ __forceinline__ __half2 clamp1h2(__half2 v) {
    H2U a; a.h = v;
    unsigned int lo = 0xBC00BC00u;   // (-1, -1) fp16
    unsigned int hi = 0x3C003C00u;   // (+1, +1) fp16
    unsigned int t, r;
    asm("v_pk_max_f16 %0, %1, %2" : "=v"(t) : "v"(a.u), "v"(lo));
    asm("v_pk_min_f16 %0, %1, %2" : "=v"(r) : "v"(t),   "v"(hi));
    H2U b; b.u = r;
    return b.h;
}

__device__ __forceinline__ __half2 shfl_up_h2(__half2 v) {
    H2U a; a.h = v;
    int s = __shfl_up((int)a.u, 1, 64);
    H2U b; b.u = (unsigned)s;
    return b.h;
}

// (hi:lo) >> 16, as __half2: result = (lo.hi, hi.lo)
__device__ __forceinline__ __half2 align16(__half2 hi, __half2 lo) {
    H2U a, b, d;
    a.h = hi; b.h = lo;
    asm("v_alignbit_b32 %0, %1, %2, 16" : "=v"(d.u) : "v"(a.u), "v"(b.u));
    return d.h;
}

// iteration 0 (p=0 -> u=x):  p = clip(tau * grad(x)); also emits x_h = fp16(x)
__global__ __launch_bounds__(512) void tv_first(const float* __restrict__ x,
                                                __half2* __restrict__ po,
                                                __half* __restrict__ xh)
{
    const int tx = threadIdx.x, ty = threadIdx.y;
    const int i = blockIdx.y * BY + ty;
    const int j = blockIdx.x * TILE_W + tx * VEC;
    const size_t idx = (size_t)i * WW + j;

    float4 xc4 = *(const float4*)(x + idx);
    float4 xd4 = make_float4(0.f, 0.f, 0.f, 0.f);
    if (i < HH - 1) xd4 = *(const float4*)(x + idx + WW);

    float c[4] = {xc4.x, xc4.y, xc4.z, xc4.w};
    float d[4] = {xd4.x, xd4.y, xd4.z, xd4.w};

    float xr = __shfl_down(c[0], 1, 64);
    if (tx == BX - 1 && j + VEC < WW) xr = x[idx + VEC];

    H2x4 o;
#pragma unroll
    for (int e = 0; e < 4; ++e) {
        float gx = (i < HH - 1) ? (d[e] - c[e]) : 0.f;
        float rn = (e < 3) ? c[e + 1] : xr;
        float gy = (j + e < WW - 1) ? (rn - c[e]) : 0.f;
        o.h2[e] = __floats2half2_rn(clip1(TAU_F * gx), clip1(TAU_F * gy));
    }
    *(float4*)(po + idx) = o.f4;

    H2x2 xs;
    xs.h2[0] = __floats2half2_rn(c[0], c[1]);
    xs.h2[1] = __floats2half2_rn(c[2], c[3]);
    *(float2*)(xh + idx) = xs.f2;
}

// -------- eight fused Chambolle steps, 2-row register strips (quad state) ---
template<bool EDGE>
__device__ __forceinline__ void iter8_body(const __half* __restrict__ xh,
                                           const __half2* __restrict__ pi,
                                           __half2* __restrict__ po,
                                           __half* pxB, __half* uT,
                                           unsigned* pyE, unsigned* uE)
{
    const int tid = threadIdx.x;
    const bool act = (tid < NT8);
    const int t = act ? tid : (NT8 - 1);
    const int s = t / NQ8;
    const int q = t - s * NQ8;
    const int r0 = blockIdx.y * TH8, c0 = blockIdx.x * TW8;
    const int gi0 = r0 - 8 + 2 * s;              // global row of strip row 0
    const int gj0 = c0 - 8 + 8 * q;              // global col of chunk elem 0
    const int gjc = EDGE ? min(max(gj0, 0), WW - 8) : gj0;

    const int lB  = s * XC8 + 8 * q;             // own boundary-row slot
    const int lBu = ((s > 0) ? (s - 1) : 0) * XC8 + 8 * q;
    const int lBd = ((s < NS8 - 1) ? (s + 1) : s) * XC8 + 8 * q;
    const int eO = t;                            // packed edge (u32 index)
    const int eL = (q > 0) ? (t - 1) : t;
    const int eR = (q < NQ8 - 1) ? (t + 1) : t;
    const bool wout = act && (s >= 4) && (s < 20) && (q >= 1) && (q <= 8);

    unsigned mdy = 0xFFFFFFFFu, mgy = 0xFFFFFFFFu;
    if (EDGE) {
        if (gj0 == 0)      mdy = 0xFFFF0000u;    // zero dy at global col 0
        if (gj0 + 8 == WW) mgy = 0x0000FFFFu;    // zero gy at global col WW-1
    }

    const __half2 tau2 = __float2half2_rn(TAU_F);
    const __half2 nC2  = __float2half2_rn(-C_LAM);
    const unsigned SEL0 = 0x05040100u;   // (a.lo16, b.lo16)
    const unsigned SELH = 0x07060302u;   // (a.hi16, b.hi16)
    const unsigned SELM = 0x05040302u;   // (a.lo16, b.hi16)

    // quad-contiguous state: b128 accesses consume these registers directly
    H2x4 X0, X1, Y0, Y1, XH0, XH1, U0, U1;

    // ---- stage A: load interleaved p + xh; deinterleave into registers ----
    {
        int gik = gi0;
        if (EDGE) gik = min(max(gik, 0), HH - 1);
        const size_t go = (size_t)gik * WW + gjc;
        H2x4 v0; v0.v4 = *(const f32x4_t*)(pi + go);
        H2x4 v1; v1.v4 = *(const f32x4_t*)(pi + go + 4);
        XH0.v4 = *(const f32x4_t*)(xh + go);
        X0.h2[0] = permh(v0.h2[1], v0.h2[0], SEL0);
        Y0.h2[0] = permh(v0.h2[1], v0.h2[0], SELH);
        X0.h2[1] = permh(v0.h2[3], v0.h2[2], SEL0);
        Y0.h2[1] = permh(v0.h2[3], v0.h2[2], SELH);
        X0.h2[2] = permh(v1.h2[1], v1.h2[0], SEL0);
        Y0.h2[2] = permh(v1.h2[1], v1.h2[0], SELH);
        X0.h2[3] = permh(v1.h2[3], v1.h2[2], SEL0);
        Y0.h2[3] = permh(v1.h2[3], v1.h2[2], SELH);
    }
    {
        int gik = gi0 + 1;
        if (EDGE) gik = min(max(gik, 0), HH - 1);
        const size_t go = (size_t)gik * WW + gjc;
        H2x4 v0; v0.v4 = *(const f32x4_t*)(pi + go);
        H2x4 v1; v1.v4 = *(const f32x4_t*)(pi + go + 4);
        XH1.v4 = *(const f32x4_t*)(xh + go);
        X1.h2[0] = permh(v0.h2[1], v0.h2[0], SEL0);
        Y1.h2[0] = permh(v0.h2[1], v0.h2[0], SELH);
        X1.h2[1] = permh(v0.h2[3], v0.h2[2], SEL0);
        Y1.h2[1] = permh(v0.h2[3], v0.h2[2], SELH);
        X1.h2[2] = permh(v1.h2[1], v1.h2[0], SEL0);
        Y1.h2[2] = permh(v1.h2[1], v1.h2[0], SELH);
        X1.h2[3] = permh(v1.h2[3], v1.h2[2], SEL0);
        Y1.h2[3] = permh(v1.h2[3], v1.h2[2], SELH);
    }

    const bool row0ok = !EDGE || (gi0 > 0);
    const bool row1ok = !EDGE || (gi0 + 1 > 0);      // row1 dx uses row0 (in-tile)
    const bool gx0ok  = !EDGE || (gi0 < HH - 1);
    const bool gx1ok  = !EDGE || (gi0 + 1 < HH - 1);

    auto publish = [&]() {
        if (act) {
            *(f32x4_t*)(pxB + lB) = X1.v4;                 // direct quad store
            pyE[eO] = h2u(permh(Y1.h2[3], Y0.h2[3], SELH));
        }
    };

    auto ustage = [&]() {
        H2x4 pu; pu.v4 = *(const f32x4_t*)(pxB + lBu);
        const __half2 L = u2h(pyE[eL]);
        // row 0
        {
            __half2 dx[4], zm[4], dy[4];
#pragma unroll
            for (int m = 0; m < 4; ++m) dx[m] = __hsub2(pu.h2[m], X0.h2[m]);
            if (EDGE && !row0ok) {
#pragma unroll
                for (int m = 0; m < 4; ++m) dx[m] = u2h(0u);
            }
            zm[0] = permh(Y0.h2[0], L, SEL0);
            zm[1] = align16(Y0.h2[1], Y0.h2[0]);
            zm[2] = align16(Y0.h2[2], Y0.h2[1]);
            zm[3] = align16(Y0.h2[3], Y0.h2[2]);
#pragma unroll
            for (int m = 0; m < 4; ++m) dy[m] = __hsub2(zm[m], Y0.h2[m]);
            if (EDGE) dy[0] = andh(dy[0], mdy);
#pragma unroll
            for (int m = 0; m < 4; ++m)
                U0.h2[m] = __hfma2(__hadd2(dx[m], dy[m]), nC2, XH0.h2[m]);
        }
        // row 1
        {
            __half2 dx[4], zm[4], dy[4];
#pragma unroll
            for (int m = 0; m < 4; ++m) dx[m] = __hsub2(X0.h2[m], X1.h2[m]);
            if (EDGE && !row1ok) {
#pragma unroll
                for (int m = 0; m < 4; ++m) dx[m] = u2h(0u);
            }
            zm[0] = permh(Y1.h2[0], L, SELM);
            zm[1] = align16(Y1.h2[1], Y1.h2[0]);
            zm[2] = align16(Y1.h2[2], Y1.h2[1]);
            zm[3] = align16(Y1.h2[3], Y1.h2[2]);
#pragma unroll
            for (int m = 0; m < 4; ++m) dy[m] = __hsub2(zm[m], Y1.h2[m]);
            if (EDGE) dy[0] = andh(dy[0], mdy);
#pragma unroll
            for (int m = 0; m < 4; ++m)
                U1.h2[m] = __hfma2(__hadd2(dx[m], dy[m]), nC2, XH1.h2[m]);
        }
        if (act) {
            *(f32x4_t*)(uT + lB) = U0.v4;                  // direct quad store
            uE[eO] = h2u(permh(U1.h2[0], U0.h2[0], SEL0));
        }
    };

    auto pstage = [&]() {
        H2x4 ud; ud.v4 = *(const f32x4_t*)(uT + lBd);
        const __half2 R = u2h(uE[eR]);
        // row 0
        {
            __half2 gx[4], zp[4], gy[4];
#pragma unroll
            for (int m = 0; m < 4; ++m) gx[m] = __hsub2(U1.h2[m], U0.h2[m]);
            if (EDGE && !gx0ok) {
#pragma unroll
                for (int m = 0; m < 4; ++m) gx[m] = u2h(0u);
            }
            zp[0] = align16(U0.h2[1], U0.h2[0]);
            zp[1] = align16(U0.h2[2], U0.h2[1]);
            zp[2] = align16(U0.h2[3], U0.h2[2]);
            zp[3] = permh(R, U0.h2[3], SELM);
#pragma unroll
            for (int m = 0; m < 4; ++m) gy[m] = __hsub2(zp[m], U0.h2[m]);
            if (EDGE) gy[3] = andh(gy[3], mgy);
#pragma unroll
            for (int m = 0; m < 4; ++m) {
                X0.h2[m] = clamp1h2(__hfma2(gx[m], tau2, X0.h2[m]));
                Y0.h2[m] = clamp1h2(__hfma2(gy[m], tau2, Y0.h2[m]));
            }
        }
        // row 1
        {
            __half2 gx[4], zp[4], gy[4];
#pragma unroll
            for (int m = 0; m < 4; ++m) gx[m] = __hsub2(ud.h2[m], U1.h2[m]);
            if (EDGE && !gx1ok) {
#pragma unroll
                for (int m = 0; m < 4; ++m) gx[m] = u2h(0u);
            }
            zp[0] = align16(U1.h2[1], U1.h2[0]);
            zp[1] = align16(U1.h2[2], U1.h2[1]);
            zp[2] = align16(U1.h2[3], U1.h2[2]);
            zp[3] = permh(R, U1.h2[3], SELH);
#pragma unroll
            for (int m = 0; m < 4; ++m) gy[m] = __hsub2(zp[m], U1.h2[m]);
            if (EDGE) gy[3] = andh(gy[3], mgy);
#pragma unroll
            for (int m = 0; m < 4; ++m) {
                X1.h2[m] = clamp1h2(__hfma2(gx[m], tau2, X1.h2[m]));
                Y1.h2[m] = clamp1h2(__hfma2(gy[m], tau2, Y1.h2[m]));
            }
        }
    };

    // rolled outer loop keeps one iteration's state live at a time
#pragma unroll 1
    for (int it = 0; it < 7; ++it) {
        publish(); __syncthreads();
        ustage();  __syncthreads();
        pstage();
    }
    // peeled final iteration, then global write of p
    publish(); __syncthreads();
    ustage();  __syncthreads();
    pstage();

    if (wout) {
        {
            const size_t go = (size_t)gi0 * WW + gj0;
            H2x4 w0, w1;
            w0.h2[0] = permh(Y0.h2[0], X0.h2[0], SEL0);
            w0.h2[1] = permh(Y0.h2[0], X0.h2[0], SELH);
            w0.h2[2] = permh(Y0.h2[1], X0.h2[1], SEL0);
            w0.h2[3] = permh(Y0.h2[1], X0.h2[1], SELH);
            w1.h2[0] = permh(Y0.h2[2], X0.h2[2], SEL0);
            w1.h2[1] = permh(Y0.h2[2], X0.h2[2], SELH);
            w1.h2[2] = permh(Y0.h2[3], X0.h2[3], SEL0);
            w1.h2[3] = permh(Y0.h2[3], X0.h2[3], SELH);
            *(f32x4_t*)(po + go)     = w0.v4;
            *(f32x4_t*)(po + go + 4) = w1.v4;
        }
        {
            const size_t go = (size_t)(gi0 + 1) * WW + gj0;
            H2x4 w0, w1;
            w0.h2[0] = permh(Y1.h2[0], X1.h2[0], SEL0);
            w0.h2[1] = permh(Y1.h2[0], X1.h2[0], SELH);
            w0.h2[2] = permh(Y1.h2[1], X1.h2[1], SEL0);
            w0.h2[3] = permh(Y1.h2[1], X1.h2[1], SELH);
            w1.h2[0] = permh(Y1.h2[2], X1.h2[2], SEL0);
            w1.h2[1] = permh(Y1.h2[2], X1.h2[2], SELH);
            w1.h2[2] = permh(Y1.h2[3], X1.h2[3], SEL0);
            w1.h2[3] = permh(Y1.h2[3], X1.h2[3], SELH);
            *(f32x4_t*)(po + go)     = w0.v4;
            *(f32x4_t*)(po + go + 4) = w1.v4;
        }
    }
}

__global__ __launch_bounds__(256) void tv_iter8(const __half* __restrict__ xh,
                                                const __half2* __restrict__ pi,
                                                __half2* __restrict__ po)
{
    __shared__ __align__(16) __half   pxB[NS8 * XC8];
    __shared__ __align__(16) __half   uT [NS8 * XC8];
    __shared__ __align__(8)  unsigned pyE[NT8];
    __shared__ __align__(8)  unsigned uE [NT8];

    const bool edge = (blockIdx.x == 0) || (blockIdx.x == gridDim.x - 1) ||
                      (blockIdx.y == 0) || (blockIdx.y == gridDim.y - 1);
    if (!edge) iter8_body<false>(xh, pi, po, pxB, uT, pyE, uE);
    else       iter8_body<true >(xh, pi, po, pxB, uT, pyE, uE);
}

// -------- final: one more p-update (p49 -> p50) fused with the output --------
__global__ __launch_bounds__(256) void tv_last(const __half* __restrict__ xh,
                                               const float* __restrict__ x,
                                               const __half2* __restrict__ pi,
                                               float* __restrict__ out)
{
    __shared__ __half2 sp0[LSZ];
    __shared__ __half2 sp1[LSZ];
    __shared__ float   su [LSZ];

    const int tid  = threadIdx.x;
    const int lane = tid & 63;
    const int r0 = blockIdx.y * TH2;
    const int c0 = blockIdx.x * TW2;
    const __half2 tau2 = __float2half2_rn(TAU_F);

    int lb[3], lup[3], llf[3], ldn[3], lrt[3], gj0a[3], gofs[3];
    bool wr[3];
#pragma unroll
    for (int r = 0; r < 3; ++r) {
        int slot = tid + 256 * r;
        wr[r] = (slot < NSL);
        if (slot >= NSL) slot = NSL - 1;
        int cr = slot / NCH;
        int cc = slot - cr * NCH;
        int gi  = r0 - 2 + cr;
        int gj0 = c0 - 4 + cc * 4;
        int gic = min(max(gi, 0), HH - 1);
        int gjc = min(max(gj0, 0), WW - 4);
        gofs[r] = gic * WW + gjc;
        int l   = cr * ECC + cc * 4;
        lb[r]  = l;
        lup[r] = (cr > 0) ? l - ECC : l;
        llf[r] = (l > 0) ? l - 1 : 0;
        ldn[r] = (cr < ERR - 1) ? l + ECC : l;
        lrt[r] = min(l + 4, LSZ - 1);
        gj0a[r] = gj0;
    }

    __half2 c2[3][4];
    H2x2    xc[3];
#pragma unroll
    for (int r = 0; r < 3; ++r) {
        H2x4 v; v.f4 = *(const float4*)(pi + gofs[r]);
        xc[r].f2    = *(const float2*)(xh + gofs[r]);
        if (wr[r]) *(float4*)&sp0[lb[r]] = v.f4;
        c2[r][0] = v.h2[0]; c2[r][1] = v.h2[1];
        c2[r][2] = v.h2[2]; c2[r][3] = v.h2[3];
    }
    __syncthreads();

    float u1v[3][4];
#pragma unroll
    for (int r = 0; r < 3; ++r) {
        H2x4 up; up.f4 = *(float4*)&sp0[lup[r]];
        __half2 lf = shfl_up_h2(c2[r][3]);
        if (lane == 0) lf = sp0[llf[r]];
        float xs[4] = {__low2float(xc[r].h2[0]), __high2float(xc[r].h2[0]),
                       __low2float(xc[r].h2[1]), __high2float(xc[r].h2[1])};
        float4 w;
        float* wp = &w.x;
#pragma unroll
        for (int e = 0; e < 4; ++e) {
            __half2 cc = c2[r][e];
            __half2 le = (e == 0) ? lf : c2[r][e - 1];
            float dx = __low2float(up.h2[e]) - __low2float(cc);
            float dy = __high2float(le) - __high2float(cc);
            dy = (gj0a[r] + e > 0) ? dy : 0.f;
            float u = xs[e] - C_LAM * (dx + dy);
            u1v[r][e] = u;
            wp[e] = u;
        }
        if (wr[r]) *(float4*)&su[lb[r]] = w;
    }
    __syncthreads();

#pragma unroll
    for (int r = 0; r < 3; ++r) {
        float4 dn4 = *(float4*)&su[ldn[r]];
        float urr = __shfl_down(u1v[r][0], 1, 64);
        if (lane == 63) urr = su[lrt[r]];
        float dn[4] = {dn4.x, dn4.y, dn4.z, dn4.w};
        H2x4 w;
#pragma unroll
        for (int e = 0; e < 4; ++e) {
            float uc = u1v[r][e];
            float gx = dn[e] - uc;
            float rt = (e == 3) ? urr : u1v[r][e + 1];
            float gy = (gj0a[r] + e < WW - 1) ? (rt - uc) : 0.f;
            __half2 g = __float22half2_rn(make_float2(gx, gy));
            w.h2[e] = clamp1h2(__hfma2(g, tau2, c2[r][e]));
        }
        if (wr[r]) *(float4*)&sp1[lb[r]] = w.f4;
    }
    __syncthreads();

    // out = x - c*div(p50) on interior
#pragma unroll
    for (int r = 0; r < 2; ++r) {
        int slot = tid + 256 * r;
        int ir = slot >> 4, icc = slot & 15;
        int er = ir + 2, ec = icc * 4 + 4;
        int l  = er * ECC + ec;
        int gi = r0 + ir, gj = c0 + icc * 4;

        H2x4 pc_; pc_.f4 = *(float4*)&sp1[l];
        H2x4 pu_; pu_.f4 = *(float4*)&sp1[l - ECC];
        __half2 plf = shfl_up_h2(pc_.h2[3]);
        if ((tid & 15) == 0) plf = sp1[l - 1];

        float4 xr4 = *(const float4*)(x + (size_t)gi * WW + gj);
        float xv[4] = {xr4.x, xr4.y, xr4.z, xr4.w};
        float o[4];
#pragma unroll
        for (int e = 0; e < 4; ++e) {
            __half2 cc = pc_.h2[e];
            __half2 le = (e == 0) ? plf : pc_.h2[e - 1];
            float dx = __low2float(pu_.h2[e]) - __low2float(cc);
            dx = (gi > 0) ? dx : 0.f;
            float dy = __high2float(le) - __high2float(cc);
            dy = (gj + e > 0) ? dy : 0.f;
            o[e] = xv[e] - C_LAM * (dx + dy);
        }
        *(float4*)(out + (size_t)gi * WW + gj) = make_float4(o[0], o[1], o[2], o[3]);
    }
}

extern "C" void kernel_launch(void* const* d_in, const int* in_sizes, int n_in,
                              void* d_out, int out_size, void* d_ws, size_t ws_size,
                              hipStream_t stream)
{
    const float* x = (const float*)d_in[0];
    float* out = (float*)d_out;
    const size_t N = (size_t)HH * (size_t)WW;

    // ws layout: pA (64 MiB) | pB (64 MiB) | x_h (32 MiB)
    __half2* pA = (__half2*)d_ws;
    __half2* pB = pA + N;
    __half*  xh = (__half*)(pB + N);

    dim3 b1(BX, BY), g1(WW / TILE_W, HH / BY);
    dim3 b8(256),    g8(WW / TW8, HH / TH8);
    dim3 bL(256),    gL(WW / TW2, HH / TH2);

    tv_first<<<g1, b1, 0, stream>>>(x, pA, xh);              // iter 1
    __half2 *pin = pA, *pout = pB;
    for (int p = 0; p < 6; ++p) {                            // iters 2..49 (6x8)
        tv_iter8<<<g8, b8, 0, stream>>>(xh, pin, pout);
        __half2* t = pin; pin = pout; pout = t;
    }
    tv_last<<<gL, bL, 0, stream>>>(xh, x, pin, out);         // iter 50 + output
}

// Round 18
// 473.412 us; speedup vs baseline: 1.0944x; 1.0047x over previous
//
#include <hip/hip_runtime.h>
#include <hip/hip_fp16.h>

#define HH 4096
#define WW 4096

constexpr float C_LAM = 0.1f;   // ALPHA * LAMDA
constexpr float TAU_F = 0.25f;

// ---- first-iteration kernel geometry ----
#define BX 64
#define BY 8
#define VEC 4
#define TILE_W (BX * VEC)       // 256 cols per block

// ---- tv_last (2-ring) geometry ----
#define TW2 64
#define TH2 32
#define ERR 36
#define ECC 72
#define NCH (ECC / 4)
#define NSL (ERR * NCH)         // 648
#define LSZ (ERR * ECC)         // 2592

// ---- tv_iter8 (8-step, register-strip v3) geometry ----
// 2-row x 8-px strips in registers. R13-R17 lesson: with default occupancy
// target (8 waves/EU) the arch-VGPR budget is 64; peak live state ~60-65
// straddles it and the allocator spills ~70 regs to AGPRs (v_accvgpr moves
// = 2.2x VALU, measured). __launch_bounds__(256, 4) lowers the target to
// 4 waves/EU -> 128-VGPR cap -> state fits in arch VGPRs.
#define TH8 32                  // interior rows
#define TW8 64                  // interior cols
#define XC8 80                  // extended cols [c0-8, c0+71]
#define NS8 24                  // 2-row strips over 48 extended rows
#define NQ8 10                  // 8-px chunks per row
#define NT8 240                 // active threads = NS8*NQ8

typedef float    __attribute__((ext_vector_type(4))) f32x4_t;
typedef float    __attribute__((ext_vector_type(2))) f32x2_t;

union H2x4 { float4 f4; f32x4_t v4; __half2 h2[4]; unsigned u32[4]; };
union H2x2 { float2 f2; f32x2_t v2; __half2 h2[2]; unsigned u32[2]; };
union H2U  { __half2 h; unsigned int u; };

__device__ __forceinline__ float clip1(float v) {
    return fminf(1.0f, fmaxf(-1.0f, v));
}

__device__ __forceinline__ unsigned h2u(__half2 h) { H2U a; a.h = h; return a.u; }
__device__ __forceinline__ __half2  u2h(unsigned u){ H2U a; a.u = u; return a.h; }

// v_perm_b32: result bytes select from {a(hi):b(lo)}; sel byte i in 0-3 -> b, 4-7 -> a
__device__ __forceinline__ __half2 permh(__half2 a, __half2 b, unsigned sel) {
    unsigned d;
    asm("v_perm_b32 %0, %1, %2, %3" : "=v"(d) : "v"(h2u(a)), "v"(h2u(b)), "v"(sel));
    return u2h(d);
}
__device__ __forceinline__ __half2 andh(__half2 v, unsigned m) { return u2h(h2u(v) & m); }

// packed clamp to [-1,1] (no __hmax2/__hmin2 in ROCm 7.2 headers)
__device__ __forceinline__ __half2 clamp1h2(__half2 v) {
    H2U a; a.h = v;
    unsigned int lo = 0xBC00BC00u;   // (-1, -1) fp16
    unsigned int hi = 0x3C003C00u;   // (+1, +1) fp16
    unsigned int t, r;
    asm("v_pk_max_f16 %0, %1, %2" : "=v"(t) : "v"(a.u), "v"(lo));
    asm("v_pk_min_f16 %0, %1, %2" : "=v"(r) : "v"(t),   "v"(hi));
    H2U b; b.u = r;
    return b.h;
}

__device__ __forceinline__ __half2 shfl_up_h2(__half2 v) {
    H2U a; a.h = v;
    int s = __shfl_up((int)a.u, 1, 64);
    H2U b; b.u = (unsigned)s;
    return b.h;
}

// (hi:lo) >> 16, as __half2: result = (lo.hi, hi.lo)
__device__ __forceinline__ __half2 align16(__half2 hi, __half2 lo) {
    H2U a, b, d;
    a.h = hi; b.h = lo;
    asm("v_alignbit_b32 %0, %1, %2, 16" : "=v"(d.u) : "v"(a.u), "v"(b.u));
    return d.h;
}

// iteration 0 (p=0 -> u=x):  p = clip(tau * grad(x)); also emits x_h = fp16(x)
__global__ __launch_bounds__(512) void tv_first(const float* __restrict__ x,
                                                __half2* __restrict__ po,
                                                __half* __restrict__ xh)
{
    const int tx = threadIdx.x, ty = threadIdx.y;
    const int i = blockIdx.y * BY + ty;
    const int j = blockIdx.x * TILE_W + tx * VEC;
    const size_t idx = (size_t)i * WW + j;

    float4 xc4 = *(const float4*)(x + idx);
    float4 xd4 = make_float4(0.f, 0.f, 0.f, 0.f);
    if (i < HH - 1) xd4 = *(const float4*)(x + idx + WW);

    float c[4] = {xc4.x, xc4.y, xc4.z, xc4.w};
    float d[4] = {xd4.x, xd4.y, xd4.z, xd4.w};

    float xr = __shfl_down(c[0], 1, 64);
    if (tx == BX - 1 && j + VEC < WW) xr = x[idx + VEC];

    H2x4 o;
#pragma unroll
    for (int e = 0; e < 4; ++e) {
        float gx = (i < HH - 1) ? (d[e] - c[e]) : 0.f;
        float rn = (e < 3) ? c[e + 1] : xr;
        float gy = (j + e < WW - 1) ? (rn - c[e]) : 0.f;
        o.h2[e] = __floats2half2_rn(clip1(TAU_F * gx), clip1(TAU_F * gy));
    }
    *(float4*)(po + idx) = o.f4;

    H2x2 xs;
    xs.h2[0] = __floats2half2_rn(c[0], c[1]);
    xs.h2[1] = __floats2half2_rn(c[2], c[3]);
    *(float2*)(xh + idx) = xs.f2;
}

// -------- eight fused Chambolle steps, 2-row register strips (quad state) ---
template<bool EDGE>
__device__ __forceinline__ void iter8_body(const __half* __restrict__ xh,
                                           const __half2* __restrict__ pi,
                                           __half2* __restrict__ po,
                                           __half* pxB, __half* uT,
                                           unsigned* pyE, unsigned* uE)
{
    const int tid = threadIdx.x;
    const bool act = (tid < NT8);
    const int t = act ? tid : (NT8 - 1);
    const int s = t / NQ8;
    const int q = t - s * NQ8;
    const int r0 = blockIdx.y * TH8, c0 = blockIdx.x * TW8;
    const int gi0 = r0 - 8 + 2 * s;              // global row of strip row 0
    const int gj0 = c0 - 8 + 8 * q;              // global col of chunk elem 0
    const int gjc = EDGE ? min(max(gj0, 0), WW - 8) : gj0;

    const int lB  = s * XC8 + 8 * q;             // own boundary-row slot
    const int lBu = ((s > 0) ? (s - 1) : 0) * XC8 + 8 * q;
    const int lBd = ((s < NS8 - 1) ? (s + 1) : s) * XC8 + 8 * q;
    const int eO = t;                            // packed edge (u32 index)
    const int eL = (q > 0) ? (t - 1) : t;
    const int eR = (q < NQ8 - 1) ? (t + 1) : t;
    const bool wout = act && (s >= 4) && (s < 20) && (q >= 1) && (q <= 8);

    unsigned mdy = 0xFFFFFFFFu, mgy = 0xFFFFFFFFu;
    if (EDGE) {
        if (gj0 == 0)      mdy = 0xFFFF0000u;    // zero dy at global col 0
        if (gj0 + 8 == WW) mgy = 0x0000FFFFu;    // zero gy at global col WW-1
    }

    const __half2 tau2 = __float2half2_rn(TAU_F);
    const __half2 nC2  = __float2half2_rn(-C_LAM);
    const unsigned SEL0 = 0x05040100u;   // (a.lo16, b.lo16)
    const unsigned SELH = 0x07060302u;   // (a.hi16, b.hi16)
    const unsigned SELM = 0x05040302u;   // (a.lo16, b.hi16)

    // quad-contiguous state: b128 accesses consume these registers directly
    H2x4 X0, X1, Y0, Y1, XH0, XH1, U0, U1;

    // ---- stage A: load interleaved p + xh; deinterleave into registers ----
    {
        int gik = gi0;
        if (EDGE) gik = min(max(gik, 0), HH - 1);
        const size_t go = (size_t)gik * WW + gjc;
        H2x4 v0; v0.v4 = *(const f32x4_t*)(pi + go);
        H2x4 v1; v1.v4 = *(const f32x4_t*)(pi + go + 4);
        XH0.v4 = *(const f32x4_t*)(xh + go);
        X0.h2[0] = permh(v0.h2[1], v0.h2[0], SEL0);
        Y0.h2[0] = permh(v0.h2[1], v0.h2[0], SELH);
        X0.h2[1] = permh(v0.h2[3], v0.h2[2], SEL0);
        Y0.h2[1] = permh(v0.h2[3], v0.h2[2], SELH);
        X0.h2[2] = permh(v1.h2[1], v1.h2[0], SEL0);
        Y0.h2[2] = permh(v1.h2[1], v1.h2[0], SELH);
        X0.h2[3] = permh(v1.h2[3], v1.h2[2], SEL0);
        Y0.h2[3] = permh(v1.h2[3], v1.h2[2], SELH);
    }
    {
        int gik = gi0 + 1;
        if (EDGE) gik = min(max(gik, 0), HH - 1);
        const size_t go = (size_t)gik * WW + gjc;
        H2x4 v0; v0.v4 = *(const f32x4_t*)(pi + go);
        H2x4 v1; v1.v4 = *(const f32x4_t*)(pi + go + 4);
        XH1.v4 = *(const f32x4_t*)(xh + go);
        X1.h2[0] = permh(v0.h2[1], v0.h2[0], SEL0);
        Y1.h2[0] = permh(v0.h2[1], v0.h2[0], SELH);
        X1.h2[1] = permh(v0.h2[3], v0.h2[2], SEL0);
        Y1.h2[1] = permh(v0.h2[3], v0.h2[2], SELH);
        X1.h2[2] = permh(v1.h2[1], v1.h2[0], SEL0);
        Y1.h2[2] = permh(v1.h2[1], v1.h2[0], SELH);
        X1.h2[3] = permh(v1.h2[3], v1.h2[2], SEL0);
        Y1.h2[3] = permh(v1.h2[3], v1.h2[2], SELH);
    }

    const bool row0ok = !EDGE || (gi0 > 0);
    const bool row1ok = !EDGE || (gi0 + 1 > 0);      // row1 dx uses row0 (in-tile)
    const bool gx0ok  = !EDGE || (gi0 < HH - 1);
    const bool gx1ok  = !EDGE || (gi0 + 1 < HH - 1);

    auto publish = [&]() {
        if (act) {
            *(f32x4_t*)(pxB + lB) = X1.v4;                 // direct quad store
            pyE[eO] = h2u(permh(Y1.h2[3], Y0.h2[3], SELH));
        }
    };

    auto ustage = [&]() {
        H2x4 pu; pu.v4 = *(const f32x4_t*)(pxB + lBu);
        const __half2 L = u2h(pyE[eL]);
        // row 0
        {
            __half2 dx[4], zm[4], dy[4];
#pragma unroll
            for (int m = 0; m < 4; ++m) dx[m] = __hsub2(pu.h2[m], X0.h2[m]);
            if (EDGE && !row0ok) {
#pragma unroll
                for (int m = 0; m < 4; ++m) dx[m] = u2h(0u);
            }
            zm[0] = permh(Y0.h2[0], L, SEL0);
            zm[1] = align16(Y0.h2[1], Y0.h2[0]);
            zm[2] = align16(Y0.h2[2], Y0.h2[1]);
            zm[3] = align16(Y0.h2[3], Y0.h2[2]);
#pragma unroll
            for (int m = 0; m < 4; ++m) dy[m] = __hsub2(zm[m], Y0.h2[m]);
            if (EDGE) dy[0] = andh(dy[0], mdy);
#pragma unroll
            for (int m = 0; m < 4; ++m)
                U0.h2[m] = __hfma2(__hadd2(dx[m], dy[m]), nC2, XH0.h2[m]);
        }
        // row 1
        {
            __half2 dx[4], zm[4], dy[4];
#pragma unroll
            for (int m = 0; m < 4; ++m) dx[m] = __hsub2(X0.h2[m], X1.h2[m]);
            if (EDGE && !row1ok) {
#pragma unroll
                for (int m = 0; m < 4; ++m) dx[m] = u2h(0u);
            }
            zm[0] = permh(Y1.h2[0], L, SELM);
            zm[1] = align16(Y1.h2[1], Y1.h2[0]);
            zm[2] = align16(Y1.h2[2], Y1.h2[1]);
            zm[3] = align16(Y1.h2[3], Y1.h2[2]);
#pragma unroll
            for (int m = 0; m < 4; ++m) dy[m] = __hsub2(zm[m], Y1.h2[m]);
            if (EDGE) dy[0] = andh(dy[0], mdy);
#pragma unroll
            for (int m = 0; m < 4; ++m)
                U1.h2[m] = __hfma2(__hadd2(dx[m], dy[m]), nC2, XH1.h2[m]);
        }
        if (act) {
            *(f32x4_t*)(uT + lB) = U0.v4;                  // direct quad store
            uE[eO] = h2u(permh(U1.h2[0], U0.h2[0], SEL0));
        }
    };

    auto pstage = [&]() {
        H2x4 ud; ud.v4 = *(const f32x4_t*)(uT + lBd);
        const __half2 R = u2h(uE[eR]);
        // row 0
        {
            __half2 gx[4], zp[4], gy[4];
#pragma unroll
            for (int m = 0; m < 4; ++m) gx[m] = __hsub2(U1.h2[m], U0.h2[m]);
            if (EDGE && !gx0ok) {
#pragma unroll
                for (int m = 0; m < 4; ++m) gx[m] = u2h(0u);
            }
            zp[0] = align16(U0.h2[1], U0.h2[0]);
            zp[1] = align16(U0.h2[2], U0.h2[1]);
            zp[2] = align16(U0.h2[3], U0.h2[2]);
            zp[3] = permh(R, U0.h2[3], SELM);
#pragma unroll
            for (int m = 0; m < 4; ++m) gy[m] = __hsub2(zp[m], U0.h2[m]);
            if (EDGE) gy[3] = andh(gy[3], mgy);
#pragma unroll
            for (int m = 0; m < 4; ++m) {
                X0.h2[m] = clamp1h2(__hfma2(gx[m], tau2, X0.h2[m]));
                Y0.h2[m] = clamp1h2(__hfma2(gy[m], tau2, Y0.h2[m]));
            }
        }
        // row 1
        {
            __half2 gx[4], zp[4], gy[4];
#pragma unroll
            for (int m = 0; m < 4; ++m) gx[m] = __hsub2(ud.h2[m], U1.h2[m]);
            if (EDGE && !gx1ok) {
#pragma unroll
                for (int m = 0; m < 4; ++m) gx[m] = u2h(0u);
            }
            zp[0] = align16(U1.h2[1], U1.h2[0]);
            zp[1] = align16(U1.h2[2], U1.h2[1]);
            zp[2] = align16(U1.h2[3], U1.h2[2]);
            zp[3] = permh(R, U1.h2[3], SELH);
#pragma unroll
            for (int m = 0; m < 4; ++m) gy[m] = __hsub2(zp[m], U1.h2[m]);
            if (EDGE) gy[3] = andh(gy[3], mgy);
#pragma unroll
            for (int m = 0; m < 4; ++m) {
                X1.h2[m] = clamp1h2(__hfma2(gx[m], tau2, X1.h2[m]));
                Y1.h2[m] = clamp1h2(__hfma2(gy[m], tau2, Y1.h2[m]));
            }
        }
    };

    // rolled outer loop keeps one iteration's state live at a time
#pragma unroll 1
    for (int it = 0; it < 7; ++it) {
        publish(); __syncthreads();
        ustage();  __syncthreads();
        pstage();
    }
    // peeled final iteration, then global write of p
    publish(); __syncthreads();
    ustage();  __syncthreads();
    pstage();

    if (wout) {
        {
            const size_t go = (size_t)gi0 * WW + gj0;
            H2x4 w0, w1;
            w0.h2[0] = permh(Y0.h2[0], X0.h2[0], SEL0);
            w0.h2[1] = permh(Y0.h2[0], X0.h2[0], SELH);
            w0.h2[2] = permh(Y0.h2[1], X0.h2[1], SEL0);
            w0.h2[3] = permh(Y0.h2[1], X0.h2[1], SELH);
            w1.h2[0] = permh(Y0.h2[2], X0.h2[2], SEL0);
            w1.h2[1] = permh(Y0.h2[2], X0.h2[2], SELH);
            w1.h2[2] = permh(Y0.h2[3], X0.h2[3], SEL0);
            w1.h2[3] = permh(Y0.h2[3], X0.h2[3], SELH);
            *(f32x4_t*)(po + go)     = w0.v4;
            *(f32x4_t*)(po + go + 4) = w1.v4;
        }
        {
            const size_t go = (size_t)(gi0 + 1) * WW + gj0;
            H2x4 w0, w1;
            w0.h2[0] = permh(Y1.h2[0], X1.h2[0], SEL0);
            w0.h2[1] = permh(Y1.h2[0], X1.h2[0], SELH);
            w0.h2[2] = permh(Y1.h2[1], X1.h2[1], SEL0);
            w0.h2[3] = permh(Y1.h2[1], X1.h2[1], SELH);
            w1.h2[0] = permh(Y1.h2[2], X1.h2[2], SEL0);
            w1.h2[1] = permh(Y1.h2[2], X1.h2[2], SELH);
            w1.h2[2] = permh(Y1.h2[3], X1.h2[3], SEL0);
            w1.h2[3] = permh(Y1.h2[3], X1.h2[3], SELH);
            *(f32x4_t*)(po + go)     = w0.v4;
            *(f32x4_t*)(po + go + 4) = w1.v4;
        }
    }
}

// (256, 4): min 4 waves/EU -> 128-VGPR arch cap (vs default 8 waves/EU -> 64).
// Peak live state ~60-65 regs straddles 64; at 128 it fits entirely in arch
// VGPRs, eliminating the v_accvgpr spill traffic (R13-R17: 2.2x VALU).
__global__ __launch_bounds__(256, 4) void tv_iter8(const __half* __restrict__ xh,
                                                   const __half2* __restrict__ pi,
                                                   __half2* __restrict__ po)
{
    __shared__ __align__(16) __half   pxB[NS8 * XC8];
    __shared__ __align__(16) __half   uT [NS8 * XC8];
    __shared__ __align__(8)  unsigned pyE[NT8];
    __shared__ __align__(8)  unsigned uE [NT8];

    const bool edge = (blockIdx.x == 0) || (blockIdx.x == gridDim.x - 1) ||
                      (blockIdx.y == 0) || (blockIdx.y == gridDim.y - 1);
    if (!edge) iter8_body<false>(xh, pi, po, pxB, uT, pyE, uE);
    else       iter8_body<true >(xh, pi, po, pxB, uT, pyE, uE);
}

// -------- final: one more p-update (p49 -> p50) fused with the output --------
__global__ __launch_bounds__(256) void tv_last(const __half* __restrict__ xh,
                                               const float* __restrict__ x,
                                               const __half2* __restrict__ pi,
                                               float* __restrict__ out)
{
    __shared__ __half2 sp0[LSZ];
    __shared__ __half2 sp1[LSZ];
    __shared__ float   su [LSZ];

    const int tid  = threadIdx.x;
    const int lane = tid & 63;
    const int r0 = blockIdx.y * TH2;
    const int c0 = blockIdx.x * TW2;
    const __half2 tau2 = __float2half2_rn(TAU_F);

    int lb[3], lup[3], llf[3], ldn[3], lrt[3], gj0a[3], gofs[3];
    bool wr[3];
#pragma unroll
    for (int r = 0; r < 3; ++r) {
        int slot = tid + 256 * r;
        wr[r] = (slot < NSL);
        if (slot >= NSL) slot = NSL - 1;
        int cr = slot / NCH;
        int cc = slot - cr * NCH;
        int gi  = r0 - 2 + cr;
        int gj0 = c0 - 4 + cc * 4;
        int gic = min(max(gi, 0), HH - 1);
        int gjc = min(max(gj0, 0), WW - 4);
        gofs[r] = gic * WW + gjc;
        int l   = cr * ECC + cc * 4;
        lb[r]  = l;
        lup[r] = (cr > 0) ? l - ECC : l;
        llf[r] = (l > 0) ? l - 1 : 0;
        ldn[r] = (cr < ERR - 1) ? l + ECC : l;
        lrt[r] = min(l + 4, LSZ - 1);
        gj0a[r] = gj0;
    }

    __half2 c2[3][4];
    H2x2    xc[3];
#pragma unroll
    for (int r = 0; r < 3; ++r) {
        H2x4 v; v.f4 = *(const float4*)(pi + gofs[r]);
        xc[r].f2    = *(const float2*)(xh + gofs[r]);
        if (wr[r]) *(float4*)&sp0[lb[r]] = v.f4;
        c2[r][0] = v.h2[0]; c2[r][1] = v.h2[1];
        c2[r][2] = v.h2[2]; c2[r][3] = v.h2[3];
    }
    __syncthreads();

    float u1v[3][4];
#pragma unroll
    for (int r = 0; r < 3; ++r) {
        H2x4 up; up.f4 = *(float4*)&sp0[lup[r]];
        __half2 lf = shfl_up_h2(c2[r][3]);
        if (lane == 0) lf = sp0[llf[r]];
        float xs[4] = {__low2float(xc[r].h2[0]), __high2float(xc[r].h2[0]),
                       __low2float(xc[r].h2[1]), __high2float(xc[r].h2[1])};
        float4 w;
        float* wp = &w.x;
#pragma unroll
        for (int e = 0; e < 4; ++e) {
            __half2 cc = c2[r][e];
            __half2 le = (e == 0) ? lf : c2[r][e - 1];
            float dx = __low2float(up.h2[e]) - __low2float(cc);
            float dy = __high2float(le) - __high2float(cc);
            dy = (gj0a[r] + e > 0) ? dy : 0.f;
            float u = xs[e] - C_LAM * (dx + dy);
            u1v[r][e] = u;
            wp[e] = u;
        }
        if (wr[r]) *(float4*)&su[lb[r]] = w;
    }
    __syncthreads();

#pragma unroll
    for (int r = 0; r < 3; ++r) {
        float4 dn4 = *(float4*)&su[ldn[r]];
        float urr = __shfl_down(u1v[r][0], 1, 64);
        if (lane == 63) urr = su[lrt[r]];
        float dn[4] = {dn4.x, dn4.y, dn4.z, dn4.w};
        H2x4 w;
#pragma unroll
        for (int e = 0; e < 4; ++e) {
            float uc = u1v[r][e];
            float gx = dn[e] - uc;
            float rt = (e == 3) ? urr : u1v[r][e + 1];
            float gy = (gj0a[r] + e < WW - 1) ? (rt - uc) : 0.f;
            __half2 g = __float22half2_rn(make_float2(gx, gy));
            w.h2[e] = clamp1h2(__hfma2(g, tau2, c2[r][e]));
        }
        if (wr[r]) *(float4*)&sp1[lb[r]] = w.f4;
    }
    __syncthreads();

    // out = x - c*div(p50) on interior
#pragma unroll
    for (int r = 0; r < 2; ++r) {
        int slot = tid + 256 * r;
        int ir = slot >> 4, icc = slot & 15;
        int er = ir + 2, ec = icc * 4 + 4;
        int l  = er * ECC + ec;
        int gi = r0 + ir, gj = c0 + icc * 4;

        H2x4 pc_; pc_.f4 = *(float4*)&sp1[l];
        H2x4 pu_; pu_.f4 = *(float4*)&sp1[l - ECC];
        __half2 plf = shfl_up_h2(pc_.h2[3]);
        if ((tid & 15) == 0) plf = sp1[l - 1];

        float4 xr4 = *(const float4*)(x + (size_t)gi * WW + gj);
        float xv[4] = {xr4.x, xr4.y, xr4.z, xr4.w};
        float o[4];
#pragma unroll
        for (int e = 0; e < 4; ++e) {
            __half2 cc = pc_.h2[e];
            __half2 le = (e == 0) ? plf : pc_.h2[e - 1];
            float dx = __low2float(pu_.h2[e]) - __low2float(cc);
            dx = (gi > 0) ? dx : 0.f;
            float dy = __high2float(le) - __high2float(cc);
            dy = (gj + e > 0) ? dy : 0.f;
            o[e] = xv[e] - C_LAM * (dx + dy);
        }
        *(float4*)(out + (size_t)gi * WW + gj) = make_float4(o[0], o[1], o[2], o[3]);
    }
}

extern "C" void kernel_launch(void* const* d_in, const int* in_sizes, int n_in,
                              void* d_out, int out_size, void* d_ws, size_t ws_size,
                              hipStream_t stream)
{
    const float* x = (const float*)d_in[0];
    float* out = (float*)d_out;
    const size_t N = (size_t)HH * (size_t)WW;

    // ws layout: pA (64 MiB) | pB (64 MiB) | x_h (32 MiB)
    __half2* pA = (__half2*)d_ws;
    __half2* pB = pA + N;
    __half*  xh = (__half*)(pB + N);

    dim3 b1(BX, BY), g1(WW / TILE_W, HH / BY);
    dim3 b8(256),    g8(WW / TW8, HH / TH8);
    dim3 bL(256),    gL(WW / TW2, HH / TH2);

    tv_first<<<g1, b1, 0, stream>>>(x, pA, xh);              // iter 1
    __half2 *pin = pA, *pout = pB;
    for (int p = 0; p < 6; ++p) {                            // iters 2..49 (6x8)
        tv_iter8<<<g8, b8, 0, stream>>>(xh, pin, pout);
        __half2* t = pin; pin = pout; pout = t;
    }
    tv_last<<<gL, bL, 0, stream>>>(xh, x, pin, out);         // iter 50 + output
}

// Round 19
// 472.021 us; speedup vs baseline: 1.0977x; 1.0029x over previous
//
#include <hip/hip_runtime.h>
#include <hip/hip_fp16.h>

#define HH 4096
#define WW 4096

constexpr float C_LAM = 0.1f;   // ALPHA * LAMDA
constexpr float TAU_F = 0.25f;

// ---- first-iteration kernel geometry ----
#define BX 64
#define BY 8
#define VEC 4
#define TILE_W (BX * VEC)       // 256 cols per block

// ---- tv_last (2-ring) geometry ----
#define TW2 64
#define TH2 32
#define ERR 36
#define ECC 72
#define NCH (ECC / 4)
#define NSL (ERR * NCH)         // 648
#define LSZ (ERR * ECC)         // 2592

// ---- tv_iter8 (8-step, register-strip v4) geometry ----
// R19: all inline-asm lane ops (v_perm / v_alignbit / v_pk_max/min) replaced
// with compiler INTRINSICS. Inline asm was opaque to regalloc -> copies at
// every use + state banked in AGPRs (VGPR_Count pinned 36, ~70 AGPRs,
// VALU-issue 54us vs ~13us genuine). Intrinsics give the allocator SSA.
#define TH8 32                  // interior rows
#define TW8 64                  // interior cols
#define XC8 80                  // extended cols [c0-8, c0+71]
#define NS8 24                  // 2-row strips over 48 extended rows
#define NQ8 10                  // 8-px chunks per row
#define NT8 240                 // active threads = NS8*NQ8

typedef float    __attribute__((ext_vector_type(4))) f32x4_t;
typedef float    __attribute__((ext_vector_type(2))) f32x2_t;
typedef _Float16 __attribute__((ext_vector_type(2))) h2v_t;

union H2x4 { float4 f4; f32x4_t v4; __half2 h2[4]; unsigned u32[4]; };
union H2x2 { float2 f2; f32x2_t v2; __half2 h2[2]; unsigned u32[2]; };
union H2U  { __half2 h; unsigned int u; h2v_t v; };

__device__ __forceinline__ float clip1(float v) {
    return fminf(1.0f, fmaxf(-1.0f, v));
}

__device__ __forceinline__ unsigned h2u(__half2 h) { H2U a; a.h = h; return a.u; }
__device__ __forceinline__ __half2  u2h(unsigned u){ H2U a; a.u = u; return a.h; }

// v_perm_b32 via intrinsic: sel byte i in 0-3 -> b(lo), 4-7 -> a(hi)
__device__ __forceinline__ __half2 permh(__half2 a, __half2 b, unsigned sel) {
    return u2h(__builtin_amdgcn_perm(h2u(a), h2u(b), sel));
}
__device__ __forceinline__ __half2 andh(__half2 v, unsigned m) { return u2h(h2u(v) & m); }

// packed clamp to [-1,1] via elementwise min/max on native f16x2
__device__ __forceinline__ __half2 clamp1h2(__half2 v) {
    H2U a; a.h = v;
    const h2v_t one  = {(_Float16)( 1.0f), (_Float16)( 1.0f)};
    const h2v_t none = {(_Float16)(-1.0f), (_Float16)(-1.0f)};
    a.v = __builtin_elementwise_min(__builtin_elementwise_max(a.v, none), one);
    return a.h;
}

__device__ __forceinline__ __half2 shfl_up_h2(__half2 v) {
    H2U a; a.h = v;
    int s = __shfl_up((int)a.u, 1, 64);
    H2U b; b.u = (unsigned)s;
    return b.h;
}

// (hi:lo) >> 16, as __half2: result = (lo.hi, hi.lo)
__device__ __forceinline__ __half2 align16(__half2 hi, __half2 lo) {
    return u2h(__builtin_amdgcn_alignbit(h2u(hi), h2u(lo), 16));
}

// iteration 0 (p=0 -> u=x):  p = clip(tau * grad(x)); also emits x_h = fp16(x)
__global__ __launch_bounds__(512) void tv_first(const float* __restrict__ x,
                                                __half2* __restrict__ po,
                                                __half* __restrict__ xh)
{
    const int tx = threadIdx.x, ty = threadIdx.y;
    const int i = blockIdx.y * BY + ty;
    const int j = blockIdx.x * TILE_W + tx * VEC;
    const size_t idx = (size_t)i * WW + j;

    float4 xc4 = *(const float4*)(x + idx);
    float4 xd4 = make_float4(0.f, 0.f, 0.f, 0.f);
    if (i < HH - 1) xd4 = *(const float4*)(x + idx + WW);

    float c[4] = {xc4.x, xc4.y, xc4.z, xc4.w};
    float d[4] = {xd4.x, xd4.y, xd4.z, xd4.w};

    float xr = __shfl_down(c[0], 1, 64);
    if (tx == BX - 1 && j + VEC < WW) xr = x[idx + VEC];

    H2x4 o;
#pragma unroll
    for (int e = 0; e < 4; ++e) {
        float gx = (i < HH - 1) ? (d[e] - c[e]) : 0.f;
        float rn = (e < 3) ? c[e + 1] : xr;
        float gy = (j + e < WW - 1) ? (rn - c[e]) : 0.f;
        o.h2[e] = __floats2half2_rn(clip1(TAU_F * gx), clip1(TAU_F * gy));
    }
    *(float4*)(po + idx) = o.f4;

    H2x2 xs;
    xs.h2[0] = __floats2half2_rn(c[0], c[1]);
    xs.h2[1] = __floats2half2_rn(c[2], c[3]);
    *(float2*)(xh + idx) = xs.f2;
}

// -------- eight fused Chambolle steps, 2-row register strips (quad state) ---
template<bool EDGE>
__device__ __forceinline__ void iter8_body(const __half* __restrict__ xh,
                                           const __half2* __restrict__ pi,
                                           __half2* __restrict__ po,
                                           __half* pxB, __half* uT,
                                           unsigned* pyE, unsigned* uE)
{
    const int tid = threadIdx.x;
    const bool act = (tid < NT8);
    const int t = act ? tid : (NT8 - 1);
    const int s = t / NQ8;
    const int q = t - s * NQ8;
    const int r0 = blockIdx.y * TH8, c0 = blockIdx.x * TW8;
    const int gi0 = r0 - 8 + 2 * s;              // global row of strip row 0
    const int gj0 = c0 - 8 + 8 * q;              // global col of chunk elem 0
    const int gjc = EDGE ? min(max(gj0, 0), WW - 8) : gj0;

    const int lB  = s * XC8 + 8 * q;             // own boundary-row slot
    const int lBu = ((s > 0) ? (s - 1) : 0) * XC8 + 8 * q;
    const int lBd = ((s < NS8 - 1) ? (s + 1) : s) * XC8 + 8 * q;
    const int eO = t;                            // packed edge (u32 index)
    const int eL = (q > 0) ? (t - 1) : t;
    const int eR = (q < NQ8 - 1) ? (t + 1) : t;
    const bool wout = act && (s >= 4) && (s < 20) && (q >= 1) && (q <= 8);

    unsigned mdy = 0xFFFFFFFFu, mgy = 0xFFFFFFFFu;
    if (EDGE) {
        if (gj0 == 0)      mdy = 0xFFFF0000u;    // zero dy at global col 0
        if (gj0 + 8 == WW) mgy = 0x0000FFFFu;    // zero gy at global col WW-1
    }

    const __half2 tau2 = __float2half2_rn(TAU_F);
    const __half2 nC2  = __float2half2_rn(-C_LAM);
    const unsigned SEL0 = 0x05040100u;   // (a.lo16, b.lo16)
    const unsigned SELH = 0x07060302u;   // (a.hi16, b.hi16)
    const unsigned SELM = 0x05040302u;   // (a.lo16, b.hi16)

    // quad-contiguous state: b128 accesses consume these registers directly
    H2x4 X0, X1, Y0, Y1, XH0, XH1, U0, U1;

    // ---- stage A: load interleaved p + xh; deinterleave into registers ----
    {
        int gik = gi0;
        if (EDGE) gik = min(max(gik, 0), HH - 1);
        const size_t go = (size_t)gik * WW + gjc;
        H2x4 v0; v0.v4 = *(const f32x4_t*)(pi + go);
        H2x4 v1; v1.v4 = *(const f32x4_t*)(pi + go + 4);
        XH0.v4 = *(const f32x4_t*)(xh + go);
        X0.h2[0] = permh(v0.h2[1], v0.h2[0], SEL0);
        Y0.h2[0] = permh(v0.h2[1], v0.h2[0], SELH);
        X0.h2[1] = permh(v0.h2[3], v0.h2[2], SEL0);
        Y0.h2[1] = permh(v0.h2[3], v0.h2[2], SELH);
        X0.h2[2] = permh(v1.h2[1], v1.h2[0], SEL0);
        Y0.h2[2] = permh(v1.h2[1], v1.h2[0], SELH);
        X0.h2[3] = permh(v1.h2[3], v1.h2[2], SEL0);
        Y0.h2[3] = permh(v1.h2[3], v1.h2[2], SELH);
    }
    {
        int gik = gi0 + 1;
        if (EDGE) gik = min(max(gik, 0), HH - 1);
        const size_t go = (size_t)gik * WW + gjc;
        H2x4 v0; v0.v4 = *(const f32x4_t*)(pi + go);
        H2x4 v1; v1.v4 = *(const f32x4_t*)(pi + go + 4);
        XH1.v4 = *(const f32x4_t*)(xh + go);
        X1.h2[0] = permh(v0.h2[1], v0.h2[0], SEL0);
        Y1.h2[0] = permh(v0.h2[1], v0.h2[0], SELH);
        X1.h2[1] = permh(v0.h2[3], v0.h2[2], SEL0);
        Y1.h2[1] = permh(v0.h2[3], v0.h2[2], SELH);
        X1.h2[2] = permh(v1.h2[1], v1.h2[0], SEL0);
        Y1.h2[2] = permh(v1.h2[1], v1.h2[0], SELH);
        X1.h2[3] = permh(v1.h2[3], v1.h2[2], SEL0);
        Y1.h2[3] = permh(v1.h2[3], v1.h2[2], SELH);
    }

    const bool row0ok = !EDGE || (gi0 > 0);
    const bool row1ok = !EDGE || (gi0 + 1 > 0);      // row1 dx uses row0 (in-tile)
    const bool gx0ok  = !EDGE || (gi0 < HH - 1);
    const bool gx1ok  = !EDGE || (gi0 + 1 < HH - 1);

    auto publish = [&]() {
        if (act) {
            *(f32x4_t*)(pxB + lB) = X1.v4;                 // direct quad store
            pyE[eO] = h2u(permh(Y1.h2[3], Y0.h2[3], SELH));
        }
    };

    auto ustage = [&]() {
        H2x4 pu; pu.v4 = *(const f32x4_t*)(pxB + lBu);
        const __half2 L = u2h(pyE[eL]);
        // row 0
        {
            __half2 dx[4], zm[4], dy[4];
#pragma unroll
            for (int m = 0; m < 4; ++m) dx[m] = __hsub2(pu.h2[m], X0.h2[m]);
            if (EDGE && !row0ok) {
#pragma unroll
                for (int m = 0; m < 4; ++m) dx[m] = u2h(0u);
            }
            zm[0] = permh(Y0.h2[0], L, SEL0);
            zm[1] = align16(Y0.h2[1], Y0.h2[0]);
            zm[2] = align16(Y0.h2[2], Y0.h2[1]);
            zm[3] = align16(Y0.h2[3], Y0.h2[2]);
#pragma unroll
            for (int m = 0; m < 4; ++m) dy[m] = __hsub2(zm[m], Y0.h2[m]);
            if (EDGE) dy[0] = andh(dy[0], mdy);
#pragma unroll
            for (int m = 0; m < 4; ++m)
                U0.h2[m] = __hfma2(__hadd2(dx[m], dy[m]), nC2, XH0.h2[m]);
        }
        // row 1
        {
            __half2 dx[4], zm[4], dy[4];
#pragma unroll
            for (int m = 0; m < 4; ++m) dx[m] = __hsub2(X0.h2[m], X1.h2[m]);
            if (EDGE && !row1ok) {
#pragma unroll
                for (int m = 0; m < 4; ++m) dx[m] = u2h(0u);
            }
            zm[0] = permh(Y1.h2[0], L, SELM);
            zm[1] = align16(Y1.h2[1], Y1.h2[0]);
            zm[2] = align16(Y1.h2[2], Y1.h2[1]);
            zm[3] = align16(Y1.h2[3], Y1.h2[2]);
#pragma unroll
            for (int m = 0; m < 4; ++m) dy[m] = __hsub2(zm[m], Y1.h2[m]);
            if (EDGE) dy[0] = andh(dy[0], mdy);
#pragma unroll
            for (int m = 0; m < 4; ++m)
                U1.h2[m] = __hfma2(__hadd2(dx[m], dy[m]), nC2, XH1.h2[m]);
        }
        if (act) {
            *(f32x4_t*)(uT + lB) = U0.v4;                  // direct quad store
            uE[eO] = h2u(permh(U1.h2[0], U0.h2[0], SEL0));
        }
    };

    auto pstage = [&]() {
        H2x4 ud; ud.v4 = *(const f32x4_t*)(uT + lBd);
        const __half2 R = u2h(uE[eR]);
        // row 0
        {
            __half2 gx[4], zp[4], gy[4];
#pragma unroll
            for (int m = 0; m < 4; ++m) gx[m] = __hsub2(U1.h2[m], U0.h2[m]);
            if (EDGE && !gx0ok) {
#pragma unroll
                for (int m = 0; m < 4; ++m) gx[m] = u2h(0u);
            }
            zp[0] = align16(U0.h2[1], U0.h2[0]);
            zp[1] = align16(U0.h2[2], U0.h2[1]);
            zp[2] = align16(U0.h2[3], U0.h2[2]);
            zp[3] = permh(R, U0.h2[3], SELM);
#pragma unroll
            for (int m = 0; m < 4; ++m) gy[m] = __hsub2(zp[m], U0.h2[m]);
            if (EDGE) gy[3] = andh(gy[3], mgy);
#pragma unroll
            for (int m = 0; m < 4; ++m) {
                X0.h2[m] = clamp1h2(__hfma2(gx[m], tau2, X0.h2[m]));
                Y0.h2[m] = clamp1h2(__hfma2(gy[m], tau2, Y0.h2[m]));
            }
        }
        // row 1
        {
            __half2 gx[4], zp[4], gy[4];
#pragma unroll
            for (int m = 0; m < 4; ++m) gx[m] = __hsub2(ud.h2[m], U1.h2[m]);
            if (EDGE && !gx1ok) {
#pragma unroll
                for (int m = 0; m < 4; ++m) gx[m] = u2h(0u);
            }
            zp[0] = align16(U1.h2[1], U1.h2[0]);
            zp[1] = align16(U1.h2[2], U1.h2[1]);
            zp[2] = align16(U1.h2[3], U1.h2[2]);
            zp[3] = permh(R, U1.h2[3], SELH);
#pragma unroll
            for (int m = 0; m < 4; ++m) gy[m] = __hsub2(zp[m], U1.h2[m]);
            if (EDGE) gy[3] = andh(gy[3], mgy);
#pragma unroll
            for (int m = 0; m < 4; ++m) {
                X1.h2[m] = clamp1h2(__hfma2(gx[m], tau2, X1.h2[m]));
                Y1.h2[m] = clamp1h2(__hfma2(gy[m], tau2, Y1.h2[m]));
            }
        }
    };

    // rolled outer loop keeps one iteration's state live at a time
#pragma unroll 1
    for (int it = 0; it < 7; ++it) {
        publish(); __syncthreads();
        ustage();  __syncthreads();
        pstage();
    }
    // peeled final iteration, then global write of p
    publish(); __syncthreads();
    ustage();  __syncthreads();
    pstage();

    if (wout) {
        {
            const size_t go = (size_t)gi0 * WW + gj0;
            H2x4 w0, w1;
            w0.h2[0] = permh(Y0.h2[0], X0.h2[0], SEL0);
            w0.h2[1] = permh(Y0.h2[0], X0.h2[0], SELH);
            w0.h2[2] = permh(Y0.h2[1], X0.h2[1], SEL0);
            w0.h2[3] = permh(Y0.h2[1], X0.h2[1], SELH);
            w1.h2[0] = permh(Y0.h2[2], X0.h2[2], SEL0);
            w1.h2[1] = permh(Y0.h2[2], X0.h2[2], SELH);
            w1.h2[2] = permh(Y0.h2[3], X0.h2[3], SEL0);
            w1.h2[3] = permh(Y0.h2[3], X0.h2[3], SELH);
            *(f32x4_t*)(po + go)     = w0.v4;
            *(f32x4_t*)(po + go + 4) = w1.v4;
        }
        {
            const size_t go = (size_t)(gi0 + 1) * WW + gj0;
            H2x4 w0, w1;
            w0.h2[0] = permh(Y1.h2[0], X1.h2[0], SEL0);
            w0.h2[1] = permh(Y1.h2[0], X1.h2[0], SELH);
            w0.h2[2] = permh(Y1.h2[1], X1.h2[1], SEL0);
            w0.h2[3] = permh(Y1.h2[1], X1.h2[1], SELH);
            w1.h2[0] = permh(Y1.h2[2], X1.h2[2], SEL0);
            w1.h2[1] = permh(Y1.h2[2], X1.h2[2], SELH);
            w1.h2[2] = permh(Y1.h2[3], X1.h2[3], SEL0);
            w1.h2[3] = permh(Y1.h2[3], X1.h2[3], SELH);
            *(f32x4_t*)(po + go)     = w0.v4;
            *(f32x4_t*)(po + go + 4) = w1.v4;
        }
    }
}

__global__ __launch_bounds__(256, 4) void tv_iter8(const __half* __restrict__ xh,
                                                   const __half2* __restrict__ pi,
                                                   __half2* __restrict__ po)
{
    __shared__ __align__(16) __half   pxB[NS8 * XC8];
    __shared__ __align__(16) __half   uT [NS8 * XC8];
    __shared__ __align__(8)  unsigned pyE[NT8];
    __shared__ __align__(8)  unsigned uE [NT8];

    const bool edge = (blockIdx.x == 0) || (blockIdx.x == gridDim.x - 1) ||
                      (blockIdx.y == 0) || (blockIdx.y == gridDim.y - 1);
    if (!edge) iter8_body<false>(xh, pi, po, pxB, uT, pyE, uE);
    else       iter8_body<true >(xh, pi, po, pxB, uT, pyE, uE);
}

// -------- final: one more p-update (p49 -> p50) fused with the output --------
__global__ __launch_bounds__(256) void tv_last(const __half* __restrict__ xh,
                                               const float* __restrict__ x,
                                               const __half2* __restrict__ pi,
                                               float* __restrict__ out)
{
    __shared__ __half2 sp0[LSZ];
    __shared__ __half2 sp1[LSZ];
    __shared__ float   su [LSZ];

    const int tid  = threadIdx.x;
    const int lane = tid & 63;
    const int r0 = blockIdx.y * TH2;
    const int c0 = blockIdx.x * TW2;
    const __half2 tau2 = __float2half2_rn(TAU_F);

    int lb[3], lup[3], llf[3], ldn[3], lrt[3], gj0a[3], gofs[3];
    bool wr[3];
#pragma unroll
    for (int r = 0; r < 3; ++r) {
        int slot = tid + 256 * r;
        wr[r] = (slot < NSL);
        if (slot >= NSL) slot = NSL - 1;
        int cr = slot / NCH;
        int cc = slot - cr * NCH;
        int gi  = r0 - 2 + cr;
        int gj0 = c0 - 4 + cc * 4;
        int gic = min(max(gi, 0), HH - 1);
        int gjc = min(max(gj0, 0), WW - 4);
        gofs[r] = gic * WW + gjc;
        int l   = cr * ECC + cc * 4;
        lb[r]  = l;
        lup[r] = (cr > 0) ? l - ECC : l;
        llf[r] = (l > 0) ? l - 1 : 0;
        ldn[r] = (cr < ERR - 1) ? l + ECC : l;
        lrt[r] = min(l + 4, LSZ - 1);
        gj0a[r] = gj0;
    }

    __half2 c2[3][4];
    H2x2    xc[3];
#pragma unroll
    for (int r = 0; r < 3; ++r) {
        H2x4 v; v.f4 = *(const float4*)(pi + gofs[r]);
        xc[r].f2    = *(const float2*)(xh + gofs[r]);
        if (wr[r]) *(float4*)&sp0[lb[r]] = v.f4;
        c2[r][0] = v.h2[0]; c2[r][1] = v.h2[1];
        c2[r][2] = v.h2[2]; c2[r][3] = v.h2[3];
    }
    __syncthreads();

    float u1v[3][4];
#pragma unroll
    for (int r = 0; r < 3; ++r) {
        H2x4 up; up.f4 = *(float4*)&sp0[lup[r]];
        __half2 lf = shfl_up_h2(c2[r][3]);
        if (lane == 0) lf = sp0[llf[r]];
        float xs[4] = {__low2float(xc[r].h2[0]), __high2float(xc[r].h2[0]),
                       __low2float(xc[r].h2[1]), __high2float(xc[r].h2[1])};
        float4 w;
        float* wp = &w.x;
#pragma unroll
        for (int e = 0; e < 4; ++e) {
            __half2 cc = c2[r][e];
            __half2 le = (e == 0) ? lf : c2[r][e - 1];
            float dx = __low2float(up.h2[e]) - __low2float(cc);
            float dy = __high2float(le) - __high2float(cc);
            dy = (gj0a[r] + e > 0) ? dy : 0.f;
            float u = xs[e] - C_LAM * (dx + dy);
            u1v[r][e] = u;
            wp[e] = u;
        }
        if (wr[r]) *(float4*)&su[lb[r]] = w;
    }
    __syncthreads();

#pragma unroll
    for (int r = 0; r < 3; ++r) {
        float4 dn4 = *(float4*)&su[ldn[r]];
        float urr = __shfl_down(u1v[r][0], 1, 64);
        if (lane == 63) urr = su[lrt[r]];
        float dn[4] = {dn4.x, dn4.y, dn4.z, dn4.w};
        H2x4 w;
#pragma unroll
        for (int e = 0; e < 4; ++e) {
            float uc = u1v[r][e];
            float gx = dn[e] - uc;
            float rt = (e == 3) ? urr : u1v[r][e + 1];
            float gy = (gj0a[r] + e < WW - 1) ? (rt - uc) : 0.f;
            __half2 g = __float22half2_rn(make_float2(gx, gy));
            w.h2[e] = clamp1h2(__hfma2(g, tau2, c2[r][e]));
        }
        if (wr[r]) *(float4*)&sp1[lb[r]] = w.f4;
    }
    __syncthreads();

    // out = x - c*div(p50) on interior
#pragma unroll
    for (int r = 0; r < 2; ++r) {
        int slot = tid + 256 * r;
        int ir = slot >> 4, icc = slot & 15;
        int er = ir + 2, ec = icc * 4 + 4;
        int l  = er * ECC + ec;
        int gi = r0 + ir, gj = c0 + icc * 4;

        H2x4 pc_; pc_.f4 = *(float4*)&sp1[l];
        H2x4 pu_; pu_.f4 = *(float4*)&sp1[l - ECC];
        __half2 plf = shfl_up_h2(pc_.h2[3]);
        if ((tid & 15) == 0) plf = sp1[l - 1];

        float4 xr4 = *(const float4*)(x + (size_t)gi * WW + gj);
        float xv[4] = {xr4.x, xr4.y, xr4.z, xr4.w};
        float o[4];
#pragma unroll
        for (int e = 0; e < 4; ++e) {
            __half2 cc = pc_.h2[e];
            __half2 le = (e == 0) ? plf : pc_.h2[e - 1];
            float dx = __low2float(pu_.h2[e]) - __low2float(cc);
            dx = (gi > 0) ? dx : 0.f;
            float dy = __high2float(le) - __high2float(cc);
            dy = (gj + e > 0) ? dy : 0.f;
            o[e] = xv[e] - C_LAM * (dx + dy);
        }
        *(float4*)(out + (size_t)gi * WW + gj) = make_float4(o[0], o[1], o[2], o[3]);
    }
}

extern "C" void kernel_launch(void* const* d_in, const int* in_sizes, int n_in,
                              void* d_out, int out_size, void* d_ws, size_t ws_size,
                              hipStream_t stream)
{
    const float* x = (const float*)d_in[0];
    float* out = (float*)d_out;
    const size_t N = (size_t)HH * (size_t)WW;

    // ws layout: pA (64 MiB) | pB (64 MiB) | x_h (32 MiB)
    __half2* pA = (__half2*)d_ws;
    __half2* pB = pA + N;
    __half*  xh = (__half*)(pB + N);

    dim3 b1(BX, BY), g1(WW / TILE_W, HH / BY);
    dim3 b8(256),    g8(WW / TW8, HH / TH8);
    dim3 bL(256),    gL(WW / TW2, HH / TH2);

    tv_first<<<g1, b1, 0, stream>>>(x, pA, xh);              // iter 1
    __half2 *pin = pA, *pout = pB;
    for (int p = 0; p < 6; ++p) {                            // iters 2..49 (6x8)
        tv_iter8<<<g8, b8, 0, stream>>>(xh, pin, pout);
        __half2* t = pin; pin = pout; pout = t;
    }
    tv_last<<<gL, bL, 0, stream>>>(xh, x, pin, out);         // iter 50 + output
}